// Round 20
// baseline (656.551 us; speedup 1.0000x reference)
//
#include <hip/hip_runtime.h>

typedef __attribute__((ext_vector_type(8))) short bf16x8;
typedef __attribute__((ext_vector_type(4))) float f32x4;

#define NB_ROWS 65536
#define D_EMBED 256
#define D_HID   256
#define N_EXP   8
#define D_RHID  128
#define D_IN    640
#define D_H1    2048

#define HSTR 264   // fallback h-tile stride

static __device__ __forceinline__ ushort f2bf(float f) {
  union { float f; unsigned u; } v; v.f = f;
  unsigned r = v.u + 0x7fffu + ((v.u >> 16) & 1u);
  return (ushort)(r >> 16);
}
static __device__ __forceinline__ float bf2f(ushort h) {
  union { unsigned u; float f; } v; v.u = ((unsigned)h) << 16;
  return v.f;
}
static __device__ __forceinline__ float silu_f(float x) {
  return x / (1.0f + __expf(-x));
}

// LDS K-tile [rows][64] XOR-swizzle read index
static __device__ __forceinline__ int kswz(int r, int c) {
  return r * 64 + ((((c) >> 3) ^ (r & 7)) << 3) + ((c) & 7);
}
// global column permute (same involution, applied at matrix-store time):
// image[row][gswz(row,col)] = plain[row][col]
static __device__ __forceinline__ int gswz(int r, int c) {
  return ((c) & ~63) | (((((c) >> 3) & 7) ^ ((r) & 7)) << 3) | ((c) & 7);
}

// ---------------- weight prep ----------------
// plain: [nm][R][C] f32 -> [nm][C][R] bf16  (time-MLP weights)
__global__ void prep_transpose(const float* __restrict__ src, ushort* __restrict__ dst,
                               int R, int C, int total) {
  int idx = blockIdx.x * 256 + threadIdx.x;
  if (idx >= total) return;
  int rc = R * C;
  int m = idx / rc;
  int rem = idx - m * rc;
  int r = rem / C;
  int c = rem - r * C;
  dst[m * rc + c * R + r] = f2bf(src[idx]);
}
// transpose + in-dim 64-group XOR permute keyed by out-row&7 (involution)
__global__ void prep_transpose_swz(const float* __restrict__ src, ushort* __restrict__ dst,
                                   int R, int C, int total) {
  int idx = blockIdx.x * 256 + threadIdx.x;
  if (idx >= total) return;
  int rc = R * C;
  int m = idx / rc;
  int rem = idx - m * rc;
  int r = rem / C;       // in-dim (K)
  int c = rem - r * C;   // out-dim (row)
  int p = (r & ~63) + (((((r >> 3) & 7) ^ (c & 7)) << 3) | (r & 7));
  dst[m * rc + c * R + p] = f2bf(src[idx]);
}

// ---- ALL moe staging: global_load_lds width 16, LINEAR dest (sources pre-swizzled) ----
// [128 rows][64 cols], NT=512
static __device__ __forceinline__ void glA128_512(const ushort* __restrict__ src, int ld,
                                                  int kt, ushort* dst, int tid, int w) {
  #pragma unroll
  for (int c = 0; c < 2; ++c) {
    int f = c * 8192 + tid * 16;
    int r = f >> 7, ce = (f & 127) >> 1;
    __builtin_amdgcn_global_load_lds(
        (const __attribute__((address_space(1))) void*)(src + (size_t)r * ld + kt + ce),
        (__attribute__((address_space(3))) void*)(dst + ((c * 8192 + w * 1024) >> 1)),
        16, 0, 0);
  }
}
// [256 rows][64 cols], NT=512
static __device__ __forceinline__ void glB256_512(const ushort* __restrict__ src, int ld,
                                                  int kt, ushort* dst, int tid, int w) {
  #pragma unroll
  for (int c = 0; c < 4; ++c) {
    int f = c * 8192 + tid * 16;
    int r = f >> 7, ce = (f & 127) >> 1;
    __builtin_amdgcn_global_load_lds(
        (const __attribute__((address_space(1))) void*)(src + (size_t)r * ld + kt + ce),
        (__attribute__((address_space(3))) void*)(dst + ((c * 8192 + w * 1024) >> 1)),
        16, 0, 0);
  }
}
// [128 rows][64 cols], NT=256 (router)
static __device__ __forceinline__ void glB128_256(const ushort* __restrict__ src, int ld,
                                                  int kt, ushort* dst, int tid, int w) {
  #pragma unroll
  for (int c = 0; c < 4; ++c) {
    int f = c * 4096 + tid * 16;
    int r = f >> 7, ce = (f & 127) >> 1;
    __builtin_amdgcn_global_load_lds(
        (const __attribute__((address_space(1))) void*)(src + (size_t)r * ld + kt + ce),
        (__attribute__((address_space(3))) void*)(dst + ((c * 4096 + w * 1024) >> 1)),
        16, 0, 0);
  }
}

// ---------------- time embedding MLP + build x (SWIZZLED x image) ----------------
__global__ __launch_bounds__(512) void time_x_kernel(
    const float* __restrict__ zt, const float* __restrict__ tin,
    const float* __restrict__ cond,
    const ushort* __restrict__ tw1t, const ushort* __restrict__ tw2t,
    const float* __restrict__ tb1, const float* __restrict__ tb2,
    ushort* __restrict__ x) {
  __shared__ __align__(16) ushort sE[128 * 136];
  __shared__ float sFreq[64];
  __shared__ float sB1[128];
  __shared__ float sB2[128];

  const int tid = threadIdx.x;
  const int row0 = blockIdx.x * 128;

  // z / cond -> x (bf16, column-permuted within 64-groups keyed by row&7)
  for (int ch = tid; ch < 128 * 64; ch += 512) {
    int r = ch >> 6;
    int c4 = (ch & 63) << 2;
    size_t grow = (size_t)(row0 + r);
    float4 zv = *(const float4*)&zt[grow * 256 + c4];
    ushort4 o; o.x = f2bf(zv.x); o.y = f2bf(zv.y); o.z = f2bf(zv.z); o.w = f2bf(zv.w);
    *(ushort4*)&x[grow * 640 + gswz(r, c4)] = o;
    float4 cv = *(const float4*)&cond[grow * 256 + c4];
    ushort4 o2; o2.x = f2bf(cv.x); o2.y = f2bf(cv.y); o2.z = f2bf(cv.z); o2.w = f2bf(cv.w);
    *(ushort4*)&x[grow * 640 + gswz(r, 384 + c4)] = o2;
  }

  if (tid < 64) sFreq[tid] = __expf((float)tid * (-9.210340371976184f / 63.0f));
  if (tid < 128) { sB1[tid] = tb1[tid]; sB2[tid] = tb2[tid]; }
  __syncthreads();

  {
    int r = tid >> 2;
    int qd = tid & 3;
    float tv = tin[row0 + r];
    int half = qd >> 1;
    int cbase = (qd & 1) * 32;
    ushort* er = &sE[r * 136 + half * 64 + cbase];
    #pragma unroll
    for (int c = 0; c < 32; ++c) {
      float a = tv * sFreq[cbase + c];
      float v = half ? __cosf(a) : __sinf(a);
      er[c] = f2bf(v);
    }
  }
  __syncthreads();

  const int l = tid & 63;
  const int w = tid >> 6;
  const int wm = w >> 1;
  const int wn = w & 1;
  const int lr = l & 15;
  const int lk = (l >> 4) * 8;
  const int q4 = (l >> 4) * 4;

  f32x4 acc[2][4] = {};
  #pragma unroll
  for (int kk = 0; kk < 4; ++kk) {
    int kb = kk * 32 + lk;
    bf16x8 av[2], bv[4];
    #pragma unroll
    for (int mf = 0; mf < 2; ++mf)
      av[mf] = *(const bf16x8*)&sE[(wm * 32 + mf * 16 + lr) * 136 + kb];
    #pragma unroll
    for (int nf = 0; nf < 4; ++nf)
      bv[nf] = *(const bf16x8*)&tw1t[(size_t)(wn * 64 + nf * 16 + lr) * 128 + kb];
    #pragma unroll
    for (int mf = 0; mf < 2; ++mf)
      #pragma unroll
      for (int nf = 0; nf < 4; ++nf)
        acc[mf][nf] = __builtin_amdgcn_mfma_f32_16x16x32_bf16(av[mf], bv[nf], acc[mf][nf], 0, 0, 0);
  }
  __syncthreads();
  #pragma unroll
  for (int mf = 0; mf < 2; ++mf)
    #pragma unroll
    for (int nf = 0; nf < 4; ++nf) {
      int cc = wn * 64 + nf * 16 + lr;
      #pragma unroll
      for (int rg = 0; rg < 4; ++rg) {
        int rr = wm * 32 + mf * 16 + q4 + rg;
        sE[rr * 136 + cc] = f2bf(silu_f(acc[mf][nf][rg] + sB1[cc]));
      }
    }
  __syncthreads();

  f32x4 acc2[2][4] = {};
  #pragma unroll
  for (int kk = 0; kk < 4; ++kk) {
    int kb = kk * 32 + lk;
    bf16x8 av[2], bv[4];
    #pragma unroll
    for (int mf = 0; mf < 2; ++mf)
      av[mf] = *(const bf16x8*)&sE[(wm * 32 + mf * 16 + lr) * 136 + kb];
    #pragma unroll
    for (int nf = 0; nf < 4; ++nf)
      bv[nf] = *(const bf16x8*)&tw2t[(size_t)(wn * 64 + nf * 16 + lr) * 128 + kb];
    #pragma unroll
    for (int mf = 0; mf < 2; ++mf)
      #pragma unroll
      for (int nf = 0; nf < 4; ++nf)
        acc2[mf][nf] = __builtin_amdgcn_mfma_f32_16x16x32_bf16(av[mf], bv[nf], acc2[mf][nf], 0, 0, 0);
  }
  #pragma unroll
  for (int mf = 0; mf < 2; ++mf)
    #pragma unroll
    for (int nf = 0; nf < 4; ++nf) {
      int cc = wn * 64 + nf * 16 + lr;
      #pragma unroll
      for (int rg = 0; rg < 4; ++rg) {
        int rr = wm * 32 + mf * 16 + q4 + rg;
        x[(size_t)(row0 + rr) * 640 + gswz(rr, 256 + cc)] = f2bf(acc2[mf][nf][rg] + sB2[cc]);
      }
    }
}

// ---------------- fused router: gload_lds staging + kswz reads (x, rw1t swizzled) ----------------
__global__ __launch_bounds__(256) void router_kernel(
    const ushort* __restrict__ xb, const ushort* __restrict__ rw1t,
    const float* __restrict__ rb1, const float* __restrict__ rW2,
    const float* __restrict__ rb2, float* __restrict__ gatef,
    float* __restrict__ gateo) {
  __shared__ __align__(16) ushort smA[128 * 64];
  __shared__ __align__(16) ushort smB[128 * 64];
  __shared__ __align__(16) ushort rhbuf[128 * 136];
  __shared__ float sW2[128 * 8];

  const int tid = threadIdx.x;
  const int row0 = blockIdx.x * 128;
  for (int i = tid; i < 1024; i += 256) sW2[i] = rW2[i];

  const int l = tid & 63;
  const int w = tid >> 6;
  const int wm = w >> 1, wn = w & 1;
  const int lr = l & 15, lk = (l >> 4) * 8, q4 = (l >> 4) * 4;
  const ushort* xrow = xb + (size_t)row0 * 640;

  f32x4 acc[4][4] = {};
  for (int kt = 0; kt < 640; kt += 64) {
    glB128_256(xrow, 640, kt, smA, tid, w);
    glB128_256(rw1t, 640, kt, smB, tid, w);
    __syncthreads();
    #pragma unroll
    for (int kk = 0; kk < 2; ++kk) {
      int kb = kk * 32 + lk;
      bf16x8 av[4], bv[4];
      #pragma unroll
      for (int mf = 0; mf < 4; ++mf)
        av[mf] = *(const bf16x8*)&smA[kswz(wm * 64 + mf * 16 + lr, kb)];
      #pragma unroll
      for (int nf = 0; nf < 4; ++nf)
        bv[nf] = *(const bf16x8*)&smB[kswz(wn * 64 + nf * 16 + lr, kb)];
      #pragma unroll
      for (int mf = 0; mf < 4; ++mf)
        #pragma unroll
        for (int nf = 0; nf < 4; ++nf)
          acc[mf][nf] = __builtin_amdgcn_mfma_f32_16x16x32_bf16(av[mf], bv[nf], acc[mf][nf], 0, 0, 0);
    }
    __syncthreads();
  }
  #pragma unroll
  for (int nf = 0; nf < 4; ++nf) {
    int cc = wn * 64 + nf * 16 + lr;
    float b1v = rb1[cc];
    #pragma unroll
    for (int mf = 0; mf < 4; ++mf)
      #pragma unroll
      for (int rg = 0; rg < 4; ++rg) {
        int rr = wm * 64 + mf * 16 + q4 + rg;
        rhbuf[rr * 136 + cc] = f2bf(silu_f(acc[mf][nf][rg] + b1v));
      }
  }
  __syncthreads();

  if (tid < 128) {
    float a[8];
    #pragma unroll
    for (int e = 0; e < 8; ++e) a[e] = rb2[e];
    #pragma unroll
    for (int i8 = 0; i8 < 16; ++i8) {
      bf16x8 hv = *(const bf16x8*)&rhbuf[tid * 136 + i8 * 8];
      #pragma unroll
      for (int j = 0; j < 8; ++j) {
        float h = bf2f((ushort)hv[j]);
        const float* wrow = &sW2[(i8 * 8 + j) * 8];
        #pragma unroll
        for (int e = 0; e < 8; ++e) a[e] += h * wrow[e];
      }
    }
    float mx = a[0];
    #pragma unroll
    for (int e = 1; e < 8; ++e) mx = fmaxf(mx, a[e]);
    float s = 0.f, ex[8];
    #pragma unroll
    for (int e = 0; e < 8; ++e) { ex[e] = __expf(a[e] - mx); s += ex[e]; }
    float inv = 1.f / s;
    size_t b = (size_t)(row0 + tid);
    #pragma unroll
    for (int e = 0; e < 8; ++e) {
      float g = ex[e] * inv;
      gatef[b * 8 + e] = g;
      gateo[b * 8 + e] = g;
    }
  }
}

// ======== split kernels: ALL operands gload_lds(linear) + kswz reads ========
// K1: h1 = silu(x @ W1[e] + b1[e]) -> hg (SWIZZLED image)
__global__ __launch_bounds__(512) void moe_h1_kernel(
    const ushort* __restrict__ xb, const ushort* __restrict__ w1t,
    const float* __restrict__ eb1, ushort* __restrict__ hg, int row_base) {
  __shared__ __align__(16) ushort smA[128 * 64];
  __shared__ __align__(16) ushort smB[256 * 64];

  const int tid = threadIdx.x;
  int nwg = gridDim.x;
  int flat = blockIdx.x;
  int sid = (flat & 7) * (nwg >> 3) + (flat >> 3);
  const int rb = sid >> 3;
  const int e  = sid & 7;
  const int lrow0 = rb * 128;

  const int l = tid & 63;
  const int w = tid >> 6;
  const int wm = w >> 2, wn = w & 3;
  const int lr = l & 15, lk = (l >> 4) * 8, q4 = (l >> 4) * 4;

  const ushort* xrow = xb + (size_t)(row_base + lrow0) * 640;
  const ushort* W1 = w1t + (size_t)e * (256 * 640);

  f32x4 acc[4][4] = {};
  for (int kt = 0; kt < 640; kt += 64) {
    glA128_512(xrow, 640, kt, smA, tid, w);
    glB256_512(W1, 640, kt, smB, tid, w);
    __syncthreads();
    #pragma unroll
    for (int kk = 0; kk < 2; ++kk) {
      int kb = kk * 32 + lk;
      bf16x8 av[4], bv[4];
      #pragma unroll
      for (int mf = 0; mf < 4; ++mf)
        av[mf] = *(const bf16x8*)&smA[kswz(wm * 64 + mf * 16 + lr, kb)];
      #pragma unroll
      for (int nf = 0; nf < 4; ++nf)
        bv[nf] = *(const bf16x8*)&smB[kswz(wn * 64 + nf * 16 + lr, kb)];
      #pragma unroll
      for (int mf = 0; mf < 4; ++mf)
        #pragma unroll
        for (int nf = 0; nf < 4; ++nf)
          acc[mf][nf] = __builtin_amdgcn_mfma_f32_16x16x32_bf16(av[mf], bv[nf], acc[mf][nf], 0, 0, 0);
    }
    __syncthreads();
  }
  // epilogue -> hg (swizzled image; e*256 offset drops out of keying bits)
  #pragma unroll
  for (int nf = 0; nf < 4; ++nf) {
    int cc = wn * 64 + nf * 16 + lr;
    float b1v = eb1[e * 256 + cc];
    #pragma unroll
    for (int mf = 0; mf < 4; ++mf)
      #pragma unroll
      for (int rg = 0; rg < 4; ++rg) {
        int rr = wm * 64 + mf * 16 + q4 + rg;
        hg[(size_t)(lrow0 + rr) * D_H1 + e * 256 + gswz(rr, cc)] =
            f2bf(silu_f(acc[mf][nf][rg] + b1v));
      }
  }
}

// K2: h[:, e-slice] = gate[:,e] * silu(h @ W2[e] + b2[e]) IN-PLACE (swizzled image)
__global__ __launch_bounds__(512) void moe_h2_kernel(
    ushort* __restrict__ hg, const ushort* __restrict__ w2t,
    const float* __restrict__ eb2, const float* __restrict__ gatef, int row_base) {
  __shared__ __align__(16) ushort smA[128 * 64];
  __shared__ __align__(16) ushort smB[256 * 64];
  __shared__ float sGate[128];

  const int tid = threadIdx.x;
  int nwg = gridDim.x;
  int flat = blockIdx.x;
  int sid = (flat & 7) * (nwg >> 3) + (flat >> 3);
  const int rb = sid >> 3;
  const int e  = sid & 7;
  const int lrow0 = rb * 128;

  const int l = tid & 63;
  const int w = tid >> 6;
  const int wm = w >> 2, wn = w & 3;
  const int lr = l & 15, lk = (l >> 4) * 8, q4 = (l >> 4) * 4;

  if (tid < 128) sGate[tid] = gatef[(size_t)(row_base + lrow0 + tid) * 8 + e];

  ushort* hrow = hg + (size_t)lrow0 * D_H1 + e * 256;
  const ushort* W2 = w2t + (size_t)e * (256 * 256);

  f32x4 acc[4][4] = {};
  for (int kt = 0; kt < 256; kt += 64) {
    glA128_512(hrow, D_H1, kt, smA, tid, w);
    glB256_512(W2, 256, kt, smB, tid, w);
    __syncthreads();
    #pragma unroll
    for (int kk = 0; kk < 2; ++kk) {
      int kb = kk * 32 + lk;
      bf16x8 av[4], bv[4];
      #pragma unroll
      for (int mf = 0; mf < 4; ++mf)
        av[mf] = *(const bf16x8*)&smA[kswz(wm * 64 + mf * 16 + lr, kb)];
      #pragma unroll
      for (int nf = 0; nf < 4; ++nf)
        bv[nf] = *(const bf16x8*)&smB[kswz(wn * 64 + nf * 16 + lr, kb)];
      #pragma unroll
      for (int mf = 0; mf < 4; ++mf)
        #pragma unroll
        for (int nf = 0; nf < 4; ++nf)
          acc[mf][nf] = __builtin_amdgcn_mfma_f32_16x16x32_bf16(av[mf], bv[nf], acc[mf][nf], 0, 0, 0);
    }
    __syncthreads();   // all hrow reads drained before in-place epilogue
  }
  #pragma unroll
  for (int nf = 0; nf < 4; ++nf) {
    int cc = wn * 64 + nf * 16 + lr;
    float b2v = eb2[e * 256 + cc];
    #pragma unroll
    for (int mf = 0; mf < 4; ++mf)
      #pragma unroll
      for (int rg = 0; rg < 4; ++rg) {
        int rr = wm * 64 + mf * 16 + q4 + rg;
        hrow[(size_t)rr * D_H1 + gswz(rr, cc)] =
            f2bf(silu_f(acc[mf][nf][rg] + b2v) * sGate[rr]);
      }
  }
}

// K3: velocity = g2 @ W3 (block-diag K=2048) + gate·eb3; BM=128 BN=256
__global__ __launch_bounds__(512) void moe_vel_kernel(
    const ushort* __restrict__ hg, const ushort* __restrict__ w3t,
    const float* __restrict__ eb3, const float* __restrict__ gatef,
    float* __restrict__ velout, int row_base) {
  __shared__ __align__(16) ushort smA[128 * 64];   // 16 KB
  __shared__ __align__(16) ushort smB[256 * 64];   // 32 KB
  __shared__ float sGate[128 * 8];                 //  4 KB

  const int tid = threadIdx.x;
  int nwg = gridDim.x;
  int flat = blockIdx.x;
  int sid = (flat & 7) * (nwg >> 3) + (flat >> 3);
  const int lrow0 = sid * 128;

  const int l = tid & 63;
  const int w = tid >> 6;
  const int wm = w >> 2, wn = w & 3;
  const int lr = l & 15, lk = (l >> 4) * 8, q4 = (l >> 4) * 4;

  for (int i = tid; i < 1024; i += 512) sGate[i] = gatef[(size_t)(row_base + lrow0) * 8 + i];

  const ushort* hrow = hg + (size_t)lrow0 * D_H1;
  f32x4 vacc[4][4] = {};
  __syncthreads();

  for (int kt = 0; kt < 2048; kt += 64) {
    const int e = kt >> 8;
    glA128_512(hrow, D_H1, kt, smA, tid, w);
    glB256_512(w3t + (size_t)e * (256 * 256), 256, kt & 255, smB, tid, w);
    __syncthreads();
    #pragma unroll
    for (int kk = 0; kk < 2; ++kk) {
      int kb = kk * 32 + lk;
      bf16x8 av[4], bv[4];
      #pragma unroll
      for (int mf = 0; mf < 4; ++mf)
        av[mf] = *(const bf16x8*)&smA[kswz(wm * 64 + mf * 16 + lr, kb)];
      #pragma unroll
      for (int nf = 0; nf < 4; ++nf)
        bv[nf] = *(const bf16x8*)&smB[kswz(wn * 64 + nf * 16 + lr, kb)];
      #pragma unroll
      for (int mf = 0; mf < 4; ++mf)
        #pragma unroll
        for (int nf = 0; nf < 4; ++nf)
          vacc[mf][nf] = __builtin_amdgcn_mfma_f32_16x16x32_bf16(av[mf], bv[nf], vacc[mf][nf], 0, 0, 0);
    }
    __syncthreads();
  }

  float* eL = (float*)smB;
  for (int i = tid; i < 2048; i += 512) eL[i] = eb3[i];
  __syncthreads();
  #pragma unroll
  for (int mf = 0; mf < 4; ++mf)
    #pragma unroll
    for (int rg = 0; rg < 4; ++rg) {
      int rr = wm * 64 + mf * 16 + q4 + rg;
      const float* gp = &sGate[rr * 8];
      #pragma unroll
      for (int nf = 0; nf < 4; ++nf) {
        int cc = wn * 64 + nf * 16 + lr;
        float bsum = 0.f;
        #pragma unroll
        for (int ee = 0; ee < 8; ++ee) bsum += gp[ee] * eL[ee * 256 + cc];
        velout[(size_t)(row_base + lrow0 + rr) * D_EMBED + cc] = vacc[mf][nf][rg] + bsum;
      }
    }
}

// ---- FALLBACK: fused moe; A/B gload_lds + kswz (x, weights swizzled); hbuf plain ----
__global__ __launch_bounds__(512) void moe_fused_kernel(
    const ushort* __restrict__ xb, const ushort* __restrict__ w1t,
    const ushort* __restrict__ w2t, const ushort* __restrict__ w3t,
    const float* __restrict__ eb1, const float* __restrict__ eb2,
    const float* __restrict__ eb3, const float* __restrict__ gatef,
    float* __restrict__ velout) {
  __shared__ __align__(16) ushort smA[128 * 64];
  __shared__ __align__(16) ushort smB[256 * 64];
  __shared__ __align__(16) ushort hbuf[128 * HSTR];
  __shared__ float sGate[128 * 8];
  __shared__ float sEb3[8 * 256];

  const int tid = threadIdx.x;
  const int row0 = blockIdx.x * 128;
  const int l = tid & 63;
  const int w = tid >> 6;
  const int wm = w >> 2, wn = w & 3;
  const int lr = l & 15, lk = (l >> 4) * 8, q4 = (l >> 4) * 4;

  for (int i = tid; i < 1024; i += 512) sGate[i] = gatef[(size_t)row0 * 8 + i];
  for (int i = tid; i < 2048; i += 512) sEb3[i] = eb3[i];

  const ushort* xrow = xb + (size_t)row0 * 640;
  f32x4 vacc[4][4] = {};
  __syncthreads();

  for (int e = 0; e < 8; ++e) {
    const ushort* W1 = w1t + (size_t)e * (256 * 640);
    const ushort* W2 = w2t + (size_t)e * (256 * 256);
    const ushort* W3 = w3t + (size_t)e * (256 * 256);

    f32x4 acc[4][4] = {};
    for (int kt = 0; kt < 640; kt += 64) {
      glA128_512(xrow, 640, kt, smA, tid, w);
      glB256_512(W1, 640, kt, smB, tid, w);
      __syncthreads();
      #pragma unroll
      for (int kk = 0; kk < 2; ++kk) {
        int kb = kk * 32 + lk;
        bf16x8 av[4], bv[4];
        #pragma unroll
        for (int mf = 0; mf < 4; ++mf)
          av[mf] = *(const bf16x8*)&smA[kswz(wm * 64 + mf * 16 + lr, kb)];
        #pragma unroll
        for (int nf = 0; nf < 4; ++nf)
          bv[nf] = *(const bf16x8*)&smB[kswz(wn * 64 + nf * 16 + lr, kb)];
        #pragma unroll
        for (int mf = 0; mf < 4; ++mf)
          #pragma unroll
          for (int nf = 0; nf < 4; ++nf)
            acc[mf][nf] = __builtin_amdgcn_mfma_f32_16x16x32_bf16(av[mf], bv[nf], acc[mf][nf], 0, 0, 0);
      }
      __syncthreads();
    }
    #pragma unroll
    for (int nf = 0; nf < 4; ++nf) {
      int cc = wn * 64 + nf * 16 + lr;
      float b1v = eb1[e * 256 + cc];
      #pragma unroll
      for (int mf = 0; mf < 4; ++mf)
        #pragma unroll
        for (int rg = 0; rg < 4; ++rg) {
          int rr = wm * 64 + mf * 16 + q4 + rg;
          hbuf[rr * HSTR + cc] = f2bf(silu_f(acc[mf][nf][rg] + b1v));
        }
    }
    __syncthreads();

    #pragma unroll
    for (int mf = 0; mf < 4; ++mf)
      #pragma unroll
      for (int nf = 0; nf < 4; ++nf)
        acc[mf][nf] = (f32x4){0.f, 0.f, 0.f, 0.f};
    for (int kt = 0; kt < 256; kt += 64) {
      glB256_512(W2, 256, kt, smB, tid, w);
      __syncthreads();
      #pragma unroll
      for (int kk = 0; kk < 2; ++kk) {
        int kbl = kk * 32 + lk;
        int kbh = kt + kbl;
        bf16x8 av[4], bv[4];
        #pragma unroll
        for (int mf = 0; mf < 4; ++mf)
          av[mf] = *(const bf16x8*)&hbuf[(wm * 64 + mf * 16 + lr) * HSTR + kbh];
        #pragma unroll
        for (int nf = 0; nf < 4; ++nf)
          bv[nf] = *(const bf16x8*)&smB[kswz(wn * 64 + nf * 16 + lr, kbl)];
        #pragma unroll
        for (int mf = 0; mf < 4; ++mf)
          #pragma unroll
          for (int nf = 0; nf < 4; ++nf)
            acc[mf][nf] = __builtin_amdgcn_mfma_f32_16x16x32_bf16(av[mf], bv[nf], acc[mf][nf], 0, 0, 0);
      }
      __syncthreads();
    }
    #pragma unroll
    for (int nf = 0; nf < 4; ++nf) {
      int cc = wn * 64 + nf * 16 + lr;
      float b2v = eb2[e * 256 + cc];
      #pragma unroll
      for (int mf = 0; mf < 4; ++mf)
        #pragma unroll
        for (int rg = 0; rg < 4; ++rg) {
          int rr = wm * 64 + mf * 16 + q4 + rg;
          float gv = sGate[rr * 8 + e];
          hbuf[rr * HSTR + cc] = f2bf(silu_f(acc[mf][nf][rg] + b2v) * gv);
        }
    }
    __syncthreads();

    for (int kt = 0; kt < 256; kt += 64) {
      glB256_512(W3, 256, kt, smB, tid, w);
      __syncthreads();
      #pragma unroll
      for (int kk = 0; kk < 2; ++kk) {
        int kbl = kk * 32 + lk;
        int kbh = kt + kbl;
        bf16x8 av[4], bv[4];
        #pragma unroll
        for (int mf = 0; mf < 4; ++mf)
          av[mf] = *(const bf16x8*)&hbuf[(wm * 64 + mf * 16 + lr) * HSTR + kbh];
        #pragma unroll
        for (int nf = 0; nf < 4; ++nf)
          bv[nf] = *(const bf16x8*)&smB[kswz(wn * 64 + nf * 16 + lr, kbl)];
        #pragma unroll
        for (int mf = 0; mf < 4; ++mf)
          #pragma unroll
          for (int nf = 0; nf < 4; ++nf)
            vacc[mf][nf] = __builtin_amdgcn_mfma_f32_16x16x32_bf16(av[mf], bv[nf], vacc[mf][nf], 0, 0, 0);
      }
      __syncthreads();
    }
  }

  #pragma unroll
  for (int mf = 0; mf < 4; ++mf)
    #pragma unroll
    for (int rg = 0; rg < 4; ++rg) {
      int rr = wm * 64 + mf * 16 + q4 + rg;
      const float* gp = &sGate[rr * 8];
      #pragma unroll
      for (int nf = 0; nf < 4; ++nf) {
        int cc = wn * 64 + nf * 16 + lr;
        float bsum = 0.f;
        #pragma unroll
        for (int ee = 0; ee < 8; ++ee) bsum += gp[ee] * sEb3[ee * 256 + cc];
        velout[(size_t)(row0 + rr) * D_EMBED + cc] = vacc[mf][nf][rg] + bsum;
      }
    }
}

extern "C" void kernel_launch(void* const* d_in, const int* in_sizes, int n_in,
                              void* d_out, int out_size, void* d_ws, size_t ws_size,
                              hipStream_t stream) {
  const float* zt   = (const float*)d_in[0];
  const float* tin  = (const float*)d_in[1];
  const float* cond = (const float*)d_in[2];
  const float* tW1  = (const float*)d_in[3];
  const float* tb1  = (const float*)d_in[4];
  const float* tW2  = (const float*)d_in[5];
  const float* tb2  = (const float*)d_in[6];
  const float* eW1  = (const float*)d_in[7];
  const float* eb1  = (const float*)d_in[8];
  const float* eW2  = (const float*)d_in[9];
  const float* eb2  = (const float*)d_in[10];
  const float* eW3  = (const float*)d_in[11];
  const float* eb3  = (const float*)d_in[12];
  const float* rW1  = (const float*)d_in[13];
  const float* rb1  = (const float*)d_in[14];
  const float* rW2  = (const float*)d_in[15];
  const float* rb2  = (const float*)d_in[16];

  char* wp = (char*)d_ws;
  ushort* xb    = (ushort*)wp; wp += (size_t)NB_ROWS * D_IN * 2;
  float*  gatef = (float*)wp;  wp += (size_t)NB_ROWS * 8 * 4;
  ushort* w1t   = (ushort*)wp; wp += (size_t)N_EXP * D_HID * D_IN * 2;
  ushort* w2t   = (ushort*)wp; wp += (size_t)N_EXP * D_HID * D_HID * 2;
  ushort* w3t   = (ushort*)wp; wp += (size_t)N_EXP * D_HID * D_EMBED * 2;
  ushort* rw1t  = (ushort*)wp; wp += (size_t)D_RHID * D_IN * 2;
  ushort* tw1t  = (ushort*)wp; wp += (size_t)128 * 128 * 2;
  ushort* tw2t  = (ushort*)wp; wp += (size_t)128 * 128 * 2;
  ushort* hg    = (ushort*)wp;                       // chunk buffer tail
  size_t base = (size_t)(wp - (char*)d_ws);

  int CH = 0;
  for (int cand = NB_ROWS; cand >= 8192; cand >>= 1) {
    if (base + (size_t)cand * D_H1 * 2 <= ws_size) { CH = cand; break; }
  }

  float* velout  = (float*)d_out;
  float* gateout = velout + (size_t)NB_ROWS * D_EMBED;

  {
    int tot;
    tot = 128 * 128;
    prep_transpose<<<(tot + 255) / 256, 256, 0, stream>>>(tW1, tw1t, 128, 128, tot);
    prep_transpose<<<(tot + 255) / 256, 256, 0, stream>>>(tW2, tw2t, 128, 128, tot);
    tot = D_IN * D_RHID;
    prep_transpose_swz<<<(tot + 255) / 256, 256, 0, stream>>>(rW1, rw1t, D_IN, D_RHID, tot);
    tot = N_EXP * D_IN * D_HID;
    prep_transpose_swz<<<(tot + 255) / 256, 256, 0, stream>>>(eW1, w1t, D_IN, D_HID, tot);
    tot = N_EXP * D_HID * D_HID;
    prep_transpose_swz<<<(tot + 255) / 256, 256, 0, stream>>>(eW2, w2t, D_HID, D_HID, tot);
    tot = N_EXP * D_HID * D_EMBED;
    prep_transpose_swz<<<(tot + 255) / 256, 256, 0, stream>>>(eW3, w3t, D_HID, D_EMBED, tot);
  }

  time_x_kernel<<<512, 512, 0, stream>>>(zt, tin, cond, tw1t, tw2t, tb1, tb2, xb);
  router_kernel<<<512, 256, 0, stream>>>(xb, rw1t, rb1, rW2, rb2, gatef, gateout);

  if (CH > 0) {
    for (int r0 = 0; r0 < NB_ROWS; r0 += CH) {
      moe_h1_kernel<<<(CH / 128) * 8, 512, 0, stream>>>(xb, w1t, eb1, hg, r0);
      moe_h2_kernel<<<(CH / 128) * 8, 512, 0, stream>>>(hg, w2t, eb2, gatef, r0);
      moe_vel_kernel<<<CH / 128, 512, 0, stream>>>(hg, w3t, eb3, gatef, velout, r0);
    }
  } else {
    moe_fused_kernel<<<512, 512, 0, stream>>>(xb, w1t, w2t, w3t,
                                              eb1, eb2, eb3, gatef, velout);
  }
}

// Round 21
// 634.549 us; speedup vs baseline: 1.0347x; 1.0347x over previous
//
#include <hip/hip_runtime.h>

typedef __attribute__((ext_vector_type(8))) short bf16x8;
typedef __attribute__((ext_vector_type(4))) float f32x4;

#define NB_ROWS 65536
#define D_EMBED 256
#define D_HID   256
#define N_EXP   8
#define D_RHID  128
#define D_IN    640
#define D_H1    2048

#define HSTR 264   // fallback h-tile stride

static __device__ __forceinline__ ushort f2bf(float f) {
  union { float f; unsigned u; } v; v.f = f;
  unsigned r = v.u + 0x7fffu + ((v.u >> 16) & 1u);
  return (ushort)(r >> 16);
}
static __device__ __forceinline__ float bf2f(ushort h) {
  union { unsigned u; float f; } v; v.u = ((unsigned)h) << 16;
  return v.f;
}
static __device__ __forceinline__ float silu_f(float x) {
  return x / (1.0f + __expf(-x));
}

// LDS K-tile [rows][64] XOR-swizzle read index
static __device__ __forceinline__ int kswz(int r, int c) {
  return r * 64 + ((((c) >> 3) ^ (r & 7)) << 3) + ((c) & 7);
}
// global column permute (same involution, applied at matrix-store time)
static __device__ __forceinline__ int gswz(int r, int c) {
  return ((c) & ~63) | (((((c) >> 3) & 7) ^ ((r) & 7)) << 3) | ((c) & 7);
}

static __device__ __forceinline__ void gl16(const ushort* src, ushort* dst) {
  __builtin_amdgcn_global_load_lds(
      (const __attribute__((address_space(1))) void*)src,
      (__attribute__((address_space(3))) void*)dst, 16, 0, 0);
}

// ---------------- weight prep ----------------
__global__ void prep_transpose(const float* __restrict__ src, ushort* __restrict__ dst,
                               int R, int C, int total) {
  int idx = blockIdx.x * 256 + threadIdx.x;
  if (idx >= total) return;
  int rc = R * C;
  int m = idx / rc;
  int rem = idx - m * rc;
  int r = rem / C;
  int c = rem - r * C;
  dst[m * rc + c * R + r] = f2bf(src[idx]);
}
__global__ void prep_transpose_swz(const float* __restrict__ src, ushort* __restrict__ dst,
                                   int R, int C, int total) {
  int idx = blockIdx.x * 256 + threadIdx.x;
  if (idx >= total) return;
  int rc = R * C;
  int m = idx / rc;
  int rem = idx - m * rc;
  int r = rem / C;       // in-dim (K)
  int c = rem - r * C;   // out-dim (row)
  int p = (r & ~63) + (((((r >> 3) & 7) ^ (c & 7)) << 3) | (r & 7));
  dst[m * rc + c * R + p] = f2bf(src[idx]);
}

// [128 rows][64 cols], NT=256 (router; per-call staging kept — router is small)
static __device__ __forceinline__ void glB128_256(const ushort* __restrict__ src, int ld,
                                                  int kt, ushort* dst, int tid, int w) {
  #pragma unroll
  for (int c = 0; c < 4; ++c) {
    int f = c * 4096 + tid * 16;
    int r = f >> 7, ce = (f & 127) >> 1;
    gl16(src + (size_t)r * ld + kt + ce, dst + ((c * 4096 + w * 1024) >> 1));
  }
}

// ---------------- time embedding MLP + build x (SWIZZLED x image) ----------------
__global__ __launch_bounds__(512) void time_x_kernel(
    const float* __restrict__ zt, const float* __restrict__ tin,
    const float* __restrict__ cond,
    const ushort* __restrict__ tw1t, const ushort* __restrict__ tw2t,
    const float* __restrict__ tb1, const float* __restrict__ tb2,
    ushort* __restrict__ x) {
  __shared__ __align__(16) ushort sE[128 * 136];
  __shared__ float sFreq[64];
  __shared__ float sB1[128];
  __shared__ float sB2[128];

  const int tid = threadIdx.x;
  const int row0 = blockIdx.x * 128;

  for (int ch = tid; ch < 128 * 64; ch += 512) {
    int r = ch >> 6;
    int c4 = (ch & 63) << 2;
    size_t grow = (size_t)(row0 + r);
    float4 zv = *(const float4*)&zt[grow * 256 + c4];
    ushort4 o; o.x = f2bf(zv.x); o.y = f2bf(zv.y); o.z = f2bf(zv.z); o.w = f2bf(zv.w);
    *(ushort4*)&x[grow * 640 + gswz(r, c4)] = o;
    float4 cv = *(const float4*)&cond[grow * 256 + c4];
    ushort4 o2; o2.x = f2bf(cv.x); o2.y = f2bf(cv.y); o2.z = f2bf(cv.z); o2.w = f2bf(cv.w);
    *(ushort4*)&x[grow * 640 + gswz(r, 384 + c4)] = o2;
  }

  if (tid < 64) sFreq[tid] = __expf((float)tid * (-9.210340371976184f / 63.0f));
  if (tid < 128) { sB1[tid] = tb1[tid]; sB2[tid] = tb2[tid]; }
  __syncthreads();

  {
    int r = tid >> 2;
    int qd = tid & 3;
    float tv = tin[row0 + r];
    int half = qd >> 1;
    int cbase = (qd & 1) * 32;
    ushort* er = &sE[r * 136 + half * 64 + cbase];
    #pragma unroll
    for (int c = 0; c < 32; ++c) {
      float a = tv * sFreq[cbase + c];
      float v = half ? __cosf(a) : __sinf(a);
      er[c] = f2bf(v);
    }
  }
  __syncthreads();

  const int l = tid & 63;
  const int w = tid >> 6;
  const int wm = w >> 1;
  const int wn = w & 1;
  const int lr = l & 15;
  const int lk = (l >> 4) * 8;
  const int q4 = (l >> 4) * 4;

  f32x4 acc[2][4] = {};
  #pragma unroll
  for (int kk = 0; kk < 4; ++kk) {
    int kb = kk * 32 + lk;
    bf16x8 av[2], bv[4];
    #pragma unroll
    for (int mf = 0; mf < 2; ++mf)
      av[mf] = *(const bf16x8*)&sE[(wm * 32 + mf * 16 + lr) * 136 + kb];
    #pragma unroll
    for (int nf = 0; nf < 4; ++nf)
      bv[nf] = *(const bf16x8*)&tw1t[(size_t)(wn * 64 + nf * 16 + lr) * 128 + kb];
    #pragma unroll
    for (int mf = 0; mf < 2; ++mf)
      #pragma unroll
      for (int nf = 0; nf < 4; ++nf)
        acc[mf][nf] = __builtin_amdgcn_mfma_f32_16x16x32_bf16(av[mf], bv[nf], acc[mf][nf], 0, 0, 0);
  }
  __syncthreads();
  #pragma unroll
  for (int mf = 0; mf < 2; ++mf)
    #pragma unroll
    for (int nf = 0; nf < 4; ++nf) {
      int cc = wn * 64 + nf * 16 + lr;
      #pragma unroll
      for (int rg = 0; rg < 4; ++rg) {
        int rr = wm * 32 + mf * 16 + q4 + rg;
        sE[rr * 136 + cc] = f2bf(silu_f(acc[mf][nf][rg] + sB1[cc]));
      }
    }
  __syncthreads();

  f32x4 acc2[2][4] = {};
  #pragma unroll
  for (int kk = 0; kk < 4; ++kk) {
    int kb = kk * 32 + lk;
    bf16x8 av[2], bv[4];
    #pragma unroll
    for (int mf = 0; mf < 2; ++mf)
      av[mf] = *(const bf16x8*)&sE[(wm * 32 + mf * 16 + lr) * 136 + kb];
    #pragma unroll
    for (int nf = 0; nf < 4; ++nf)
      bv[nf] = *(const bf16x8*)&tw2t[(size_t)(wn * 64 + nf * 16 + lr) * 128 + kb];
    #pragma unroll
    for (int mf = 0; mf < 2; ++mf)
      #pragma unroll
      for (int nf = 0; nf < 4; ++nf)
        acc2[mf][nf] = __builtin_amdgcn_mfma_f32_16x16x32_bf16(av[mf], bv[nf], acc2[mf][nf], 0, 0, 0);
  }
  #pragma unroll
  for (int mf = 0; mf < 2; ++mf)
    #pragma unroll
    for (int nf = 0; nf < 4; ++nf) {
      int cc = wn * 64 + nf * 16 + lr;
      #pragma unroll
      for (int rg = 0; rg < 4; ++rg) {
        int rr = wm * 32 + mf * 16 + q4 + rg;
        x[(size_t)(row0 + rr) * 640 + gswz(rr, 256 + cc)] = f2bf(acc2[mf][nf][rg] + sB2[cc]);
      }
    }
}

// ---------------- fused router (round-20 version, passed) ----------------
__global__ __launch_bounds__(256) void router_kernel(
    const ushort* __restrict__ xb, const ushort* __restrict__ rw1t,
    const float* __restrict__ rb1, const float* __restrict__ rW2,
    const float* __restrict__ rb2, float* __restrict__ gatef,
    float* __restrict__ gateo) {
  __shared__ __align__(16) ushort smA[128 * 64];
  __shared__ __align__(16) ushort smB[128 * 64];
  __shared__ __align__(16) ushort rhbuf[128 * 136];
  __shared__ float sW2[128 * 8];

  const int tid = threadIdx.x;
  const int row0 = blockIdx.x * 128;
  for (int i = tid; i < 1024; i += 256) sW2[i] = rW2[i];

  const int l = tid & 63;
  const int w = tid >> 6;
  const int wm = w >> 1, wn = w & 1;
  const int lr = l & 15, lk = (l >> 4) * 8, q4 = (l >> 4) * 4;
  const ushort* xrow = xb + (size_t)row0 * 640;

  f32x4 acc[4][4] = {};
  for (int kt = 0; kt < 640; kt += 64) {
    glB128_256(xrow, 640, kt, smA, tid, w);
    glB128_256(rw1t, 640, kt, smB, tid, w);
    __syncthreads();
    #pragma unroll
    for (int kk = 0; kk < 2; ++kk) {
      int kb = kk * 32 + lk;
      bf16x8 av[4], bv[4];
      #pragma unroll
      for (int mf = 0; mf < 4; ++mf)
        av[mf] = *(const bf16x8*)&smA[kswz(wm * 64 + mf * 16 + lr, kb)];
      #pragma unroll
      for (int nf = 0; nf < 4; ++nf)
        bv[nf] = *(const bf16x8*)&smB[kswz(wn * 64 + nf * 16 + lr, kb)];
      #pragma unroll
      for (int mf = 0; mf < 4; ++mf)
        #pragma unroll
        for (int nf = 0; nf < 4; ++nf)
          acc[mf][nf] = __builtin_amdgcn_mfma_f32_16x16x32_bf16(av[mf], bv[nf], acc[mf][nf], 0, 0, 0);
    }
    __syncthreads();
  }
  #pragma unroll
  for (int nf = 0; nf < 4; ++nf) {
    int cc = wn * 64 + nf * 16 + lr;
    float b1v = rb1[cc];
    #pragma unroll
    for (int mf = 0; mf < 4; ++mf)
      #pragma unroll
      for (int rg = 0; rg < 4; ++rg) {
        int rr = wm * 64 + mf * 16 + q4 + rg;
        rhbuf[rr * 136 + cc] = f2bf(silu_f(acc[mf][nf][rg] + b1v));
      }
  }
  __syncthreads();

  if (tid < 128) {
    float a[8];
    #pragma unroll
    for (int e = 0; e < 8; ++e) a[e] = rb2[e];
    #pragma unroll
    for (int i8 = 0; i8 < 16; ++i8) {
      bf16x8 hv = *(const bf16x8*)&rhbuf[tid * 136 + i8 * 8];
      #pragma unroll
      for (int j = 0; j < 8; ++j) {
        float h = bf2f((ushort)hv[j]);
        const float* wrow = &sW2[(i8 * 8 + j) * 8];
        #pragma unroll
        for (int e = 0; e < 8; ++e) a[e] += h * wrow[e];
      }
    }
    float mx = a[0];
    #pragma unroll
    for (int e = 1; e < 8; ++e) mx = fmaxf(mx, a[e]);
    float s = 0.f, ex[8];
    #pragma unroll
    for (int e = 0; e < 8; ++e) { ex[e] = __expf(a[e] - mx); s += ex[e]; }
    float inv = 1.f / s;
    size_t b = (size_t)(row0 + tid);
    #pragma unroll
    for (int e = 0; e < 8; ++e) {
      float g = ex[e] * inv;
      gatef[b * 8 + e] = g;
      gateo[b * 8 + e] = g;
    }
  }
}

// ======== split kernels: pointer-incremented gload_lds staging ========
// K1: h1 = silu(x @ W1[e] + b1[e]) -> hg (swizzled image)
__global__ __launch_bounds__(512) void moe_h1_kernel(
    const ushort* __restrict__ xb, const ushort* __restrict__ w1t,
    const float* __restrict__ eb1, ushort* __restrict__ hg, int row_base) {
  __shared__ __align__(16) ushort smA[128 * 64];
  __shared__ __align__(16) ushort smB[256 * 64];

  const int tid = threadIdx.x;
  int nwg = gridDim.x;
  int flat = blockIdx.x;
  int sid = (flat & 7) * (nwg >> 3) + (flat >> 3);
  const int rb = sid >> 3;
  const int e  = sid & 7;
  const int lrow0 = rb * 128;

  const int l = tid & 63;
  const int w = tid >> 6;
  const int wm = w >> 2, wn = w & 3;
  const int lr = l & 15, lk = (l >> 4) * 8, q4 = (l >> 4) * 4;

  const ushort* xrow = xb + (size_t)(row_base + lrow0) * 640;
  const ushort* W1 = w1t + (size_t)e * (256 * 640);

  // hoisted per-thread staging pointers (advance +64 per K-step)
  const ushort* aS[2]; ushort* aD[2];
  #pragma unroll
  for (int c = 0; c < 2; ++c) {
    int f = c * 8192 + tid * 16;
    int r = f >> 7, ce = (f & 127) >> 1;
    aS[c] = xrow + (size_t)r * 640 + ce;
    aD[c] = smA + ((c * 8192 + w * 1024) >> 1);
  }
  const ushort* bS[4]; ushort* bD[4];
  #pragma unroll
  for (int c = 0; c < 4; ++c) {
    int f = c * 8192 + tid * 16;
    int r = f >> 7, ce = (f & 127) >> 1;
    bS[c] = W1 + (size_t)r * 640 + ce;
    bD[c] = smB + ((c * 8192 + w * 1024) >> 1);
  }
  // hoisted LDS read offsets (loop-invariant)
  int oA[2][4], oB[2][4];
  #pragma unroll
  for (int kk = 0; kk < 2; ++kk) {
    #pragma unroll
    for (int mf = 0; mf < 4; ++mf) oA[kk][mf] = kswz(wm * 64 + mf * 16 + lr, kk * 32 + lk);
    #pragma unroll
    for (int nf = 0; nf < 4; ++nf) oB[kk][nf] = kswz(wn * 64 + nf * 16 + lr, kk * 32 + lk);
  }

  f32x4 acc[4][4] = {};
  for (int kt = 0; kt < 640; kt += 64) {
    #pragma unroll
    for (int c = 0; c < 2; ++c) { gl16(aS[c], aD[c]); aS[c] += 64; }
    #pragma unroll
    for (int c = 0; c < 4; ++c) { gl16(bS[c], bD[c]); bS[c] += 64; }
    __syncthreads();
    #pragma unroll
    for (int kk = 0; kk < 2; ++kk) {
      bf16x8 av[4], bv[4];
      #pragma unroll
      for (int mf = 0; mf < 4; ++mf) av[mf] = *(const bf16x8*)&smA[oA[kk][mf]];
      #pragma unroll
      for (int nf = 0; nf < 4; ++nf) bv[nf] = *(const bf16x8*)&smB[oB[kk][nf]];
      #pragma unroll
      for (int mf = 0; mf < 4; ++mf)
        #pragma unroll
        for (int nf = 0; nf < 4; ++nf)
          acc[mf][nf] = __builtin_amdgcn_mfma_f32_16x16x32_bf16(av[mf], bv[nf], acc[mf][nf], 0, 0, 0);
    }
    __syncthreads();
  }
  #pragma unroll
  for (int nf = 0; nf < 4; ++nf) {
    int cc = wn * 64 + nf * 16 + lr;
    float b1v = eb1[e * 256 + cc];
    #pragma unroll
    for (int mf = 0; mf < 4; ++mf)
      #pragma unroll
      for (int rg = 0; rg < 4; ++rg) {
        int rr = wm * 64 + mf * 16 + q4 + rg;
        hg[(size_t)(lrow0 + rr) * D_H1 + e * 256 + gswz(rr, cc)] =
            f2bf(silu_f(acc[mf][nf][rg] + b1v));
      }
  }
}

// K2: h[:, e-slice] = gate[:,e] * silu(h @ W2[e] + b2[e]) IN-PLACE (swizzled image)
__global__ __launch_bounds__(512) void moe_h2_kernel(
    ushort* __restrict__ hg, const ushort* __restrict__ w2t,
    const float* __restrict__ eb2, const float* __restrict__ gatef, int row_base) {
  __shared__ __align__(16) ushort smA[128 * 64];
  __shared__ __align__(16) ushort smB[256 * 64];
  __shared__ float sGate[128];

  const int tid = threadIdx.x;
  int nwg = gridDim.x;
  int flat = blockIdx.x;
  int sid = (flat & 7) * (nwg >> 3) + (flat >> 3);
  const int rb = sid >> 3;
  const int e  = sid & 7;
  const int lrow0 = rb * 128;

  const int l = tid & 63;
  const int w = tid >> 6;
  const int wm = w >> 2, wn = w & 3;
  const int lr = l & 15, lk = (l >> 4) * 8, q4 = (l >> 4) * 4;

  if (tid < 128) sGate[tid] = gatef[(size_t)(row_base + lrow0 + tid) * 8 + e];

  ushort* hrow = hg + (size_t)lrow0 * D_H1 + e * 256;
  const ushort* W2 = w2t + (size_t)e * (256 * 256);

  const ushort* aS[2]; ushort* aD[2];
  #pragma unroll
  for (int c = 0; c < 2; ++c) {
    int f = c * 8192 + tid * 16;
    int r = f >> 7, ce = (f & 127) >> 1;
    aS[c] = hrow + (size_t)r * D_H1 + ce;
    aD[c] = smA + ((c * 8192 + w * 1024) >> 1);
  }
  const ushort* bS[4]; ushort* bD[4];
  #pragma unroll
  for (int c = 0; c < 4; ++c) {
    int f = c * 8192 + tid * 16;
    int r = f >> 7, ce = (f & 127) >> 1;
    bS[c] = W2 + (size_t)r * 256 + ce;
    bD[c] = smB + ((c * 8192 + w * 1024) >> 1);
  }
  int oA[2][4], oB[2][4];
  #pragma unroll
  for (int kk = 0; kk < 2; ++kk) {
    #pragma unroll
    for (int mf = 0; mf < 4; ++mf) oA[kk][mf] = kswz(wm * 64 + mf * 16 + lr, kk * 32 + lk);
    #pragma unroll
    for (int nf = 0; nf < 4; ++nf) oB[kk][nf] = kswz(wn * 64 + nf * 16 + lr, kk * 32 + lk);
  }

  f32x4 acc[4][4] = {};
  for (int kt = 0; kt < 256; kt += 64) {
    #pragma unroll
    for (int c = 0; c < 2; ++c) { gl16(aS[c], aD[c]); aS[c] += 64; }
    #pragma unroll
    for (int c = 0; c < 4; ++c) { gl16(bS[c], bD[c]); bS[c] += 64; }
    __syncthreads();
    #pragma unroll
    for (int kk = 0; kk < 2; ++kk) {
      bf16x8 av[4], bv[4];
      #pragma unroll
      for (int mf = 0; mf < 4; ++mf) av[mf] = *(const bf16x8*)&smA[oA[kk][mf]];
      #pragma unroll
      for (int nf = 0; nf < 4; ++nf) bv[nf] = *(const bf16x8*)&smB[oB[kk][nf]];
      #pragma unroll
      for (int mf = 0; mf < 4; ++mf)
        #pragma unroll
        for (int nf = 0; nf < 4; ++nf)
          acc[mf][nf] = __builtin_amdgcn_mfma_f32_16x16x32_bf16(av[mf], bv[nf], acc[mf][nf], 0, 0, 0);
    }
    __syncthreads();   // all hrow reads drained before in-place epilogue
  }
  #pragma unroll
  for (int nf = 0; nf < 4; ++nf) {
    int cc = wn * 64 + nf * 16 + lr;
    float b2v = eb2[e * 256 + cc];
    #pragma unroll
    for (int mf = 0; mf < 4; ++mf)
      #pragma unroll
      for (int rg = 0; rg < 4; ++rg) {
        int rr = wm * 64 + mf * 16 + q4 + rg;
        hrow[(size_t)rr * D_H1 + gswz(rr, cc)] =
            f2bf(silu_f(acc[mf][nf][rg] + b2v) * sGate[rr]);
      }
  }
}

// K3: velocity = g2 @ W3 + gate·eb3; BM=64 BN=256, 42KB LDS -> 2-3 blocks/CU
__global__ __launch_bounds__(512) void moe_vel_kernel(
    const ushort* __restrict__ hg, const ushort* __restrict__ w3t,
    const float* __restrict__ eb3, const float* __restrict__ gatef,
    float* __restrict__ velout, int row_base) {
  __shared__ __align__(16) ushort smA[64 * 64];    //  8 KB
  __shared__ __align__(16) ushort smB[256 * 64];   // 32 KB
  __shared__ float sGate[64 * 8];                  //  2 KB

  const int tid = threadIdx.x;
  int nwg = gridDim.x;
  int flat = blockIdx.x;
  int sid = (flat & 7) * (nwg >> 3) + (flat >> 3);
  const int lrow0 = sid * 64;

  const int l = tid & 63;
  const int w = tid >> 6;     // 8 waves: 2(M) x 4(N), wave tile 32x64
  const int wm = w >> 2, wn = w & 3;
  const int lr = l & 15, lk = (l >> 4) * 8, q4 = (l >> 4) * 4;

  if (tid < 512) sGate[tid] = gatef[(size_t)(row_base + lrow0) * 8 + tid];

  const ushort* hrow = hg + (size_t)lrow0 * D_H1;

  // A staging: 64x64 tile = 8KB, NT=512 -> 1 chunk of 16B/thread
  const ushort* aS; ushort* aD;
  {
    int f = tid * 16;
    int r = f >> 7, ce = (f & 127) >> 1;
    aS = hrow + (size_t)r * D_H1 + ce;
    aD = smA + ((tid * 16) >> 1);
  }
  int bR[4], bC[4]; ushort* bD[4];
  #pragma unroll
  for (int c = 0; c < 4; ++c) {
    int f = c * 8192 + tid * 16;
    bR[c] = f >> 7; bC[c] = (f & 127) >> 1;
    bD[c] = smB + ((c * 8192 + w * 1024) >> 1);
  }
  int oA[2][2], oB[2][4];
  #pragma unroll
  for (int kk = 0; kk < 2; ++kk) {
    #pragma unroll
    for (int mf = 0; mf < 2; ++mf) oA[kk][mf] = kswz(wm * 32 + mf * 16 + lr, kk * 32 + lk);
    #pragma unroll
    for (int nf = 0; nf < 4; ++nf) oB[kk][nf] = kswz(wn * 64 + nf * 16 + lr, kk * 32 + lk);
  }

  f32x4 vacc[2][4] = {};
  __syncthreads();

  for (int e = 0; e < 8; ++e) {
    const ushort* bS[4];
    const ushort* W3 = w3t + (size_t)e * (256 * 256);
    #pragma unroll
    for (int c = 0; c < 4; ++c) bS[c] = W3 + (size_t)bR[c] * 256 + bC[c];
    #pragma unroll
    for (int t4 = 0; t4 < 4; ++t4) {
      gl16(aS, aD); aS += 64;
      #pragma unroll
      for (int c = 0; c < 4; ++c) { gl16(bS[c], bD[c]); bS[c] += 64; }
      __syncthreads();
      #pragma unroll
      for (int kk = 0; kk < 2; ++kk) {
        bf16x8 av[2], bv[4];
        #pragma unroll
        for (int mf = 0; mf < 2; ++mf) av[mf] = *(const bf16x8*)&smA[oA[kk][mf]];
        #pragma unroll
        for (int nf = 0; nf < 4; ++nf) bv[nf] = *(const bf16x8*)&smB[oB[kk][nf]];
        #pragma unroll
        for (int mf = 0; mf < 2; ++mf)
          #pragma unroll
          for (int nf = 0; nf < 4; ++nf)
            vacc[mf][nf] = __builtin_amdgcn_mfma_f32_16x16x32_bf16(av[mf], bv[nf], vacc[mf][nf], 0, 0, 0);
      }
      __syncthreads();
    }
  }

  float* eL = (float*)smB;   // 8 KB; smB free after trailing barrier
  for (int i = tid; i < 2048; i += 512) eL[i] = eb3[i];
  __syncthreads();
  #pragma unroll
  for (int mf = 0; mf < 2; ++mf)
    #pragma unroll
    for (int rg = 0; rg < 4; ++rg) {
      int rr = wm * 32 + mf * 16 + q4 + rg;
      const float* gp = &sGate[rr * 8];
      #pragma unroll
      for (int nf = 0; nf < 4; ++nf) {
        int cc = wn * 64 + nf * 16 + lr;
        float bsum = 0.f;
        #pragma unroll
        for (int ee = 0; ee < 8; ++ee) bsum += gp[ee] * eL[ee * 256 + cc];
        velout[(size_t)(row_base + lrow0 + rr) * D_EMBED + cc] = vacc[mf][nf][rg] + bsum;
      }
    }
}

// ---- FALLBACK (round-20, passed): fused moe; gload_lds + kswz; hbuf plain ----
__global__ __launch_bounds__(512) void moe_fused_kernel(
    const ushort* __restrict__ xb, const ushort* __restrict__ w1t,
    const ushort* __restrict__ w2t, const ushort* __restrict__ w3t,
    const float* __restrict__ eb1, const float* __restrict__ eb2,
    const float* __restrict__ eb3, const float* __restrict__ gatef,
    float* __restrict__ velout) {
  __shared__ __align__(16) ushort smA[128 * 64];
  __shared__ __align__(16) ushort smB[256 * 64];
  __shared__ __align__(16) ushort hbuf[128 * HSTR];
  __shared__ float sGate[128 * 8];
  __shared__ float sEb3[8 * 256];

  const int tid = threadIdx.x;
  const int row0 = blockIdx.x * 128;
  const int l = tid & 63;
  const int w = tid >> 6;
  const int wm = w >> 2, wn = w & 3;
  const int lr = l & 15, lk = (l >> 4) * 8, q4 = (l >> 4) * 4;

  for (int i = tid; i < 1024; i += 512) sGate[i] = gatef[(size_t)row0 * 8 + i];
  for (int i = tid; i < 2048; i += 512) sEb3[i] = eb3[i];

  const ushort* xrow = xb + (size_t)row0 * 640;
  f32x4 vacc[4][4] = {};
  __syncthreads();

  for (int e = 0; e < 8; ++e) {
    const ushort* W1 = w1t + (size_t)e * (256 * 640);
    const ushort* W2 = w2t + (size_t)e * (256 * 256);
    const ushort* W3 = w3t + (size_t)e * (256 * 256);

    f32x4 acc[4][4] = {};
    for (int kt = 0; kt < 640; kt += 64) {
      #pragma unroll
      for (int c = 0; c < 2; ++c) {
        int f = c * 8192 + tid * 16;
        int r = f >> 7, ce = (f & 127) >> 1;
        gl16(xrow + (size_t)r * 640 + kt + ce, smA + ((c * 8192 + w * 1024) >> 1));
      }
      #pragma unroll
      for (int c = 0; c < 4; ++c) {
        int f = c * 8192 + tid * 16;
        int r = f >> 7, ce = (f & 127) >> 1;
        gl16(W1 + (size_t)r * 640 + kt + ce, smB + ((c * 8192 + w * 1024) >> 1));
      }
      __syncthreads();
      #pragma unroll
      for (int kk = 0; kk < 2; ++kk) {
        int kb = kk * 32 + lk;
        bf16x8 av[4], bv[4];
        #pragma unroll
        for (int mf = 0; mf < 4; ++mf)
          av[mf] = *(const bf16x8*)&smA[kswz(wm * 64 + mf * 16 + lr, kb)];
        #pragma unroll
        for (int nf = 0; nf < 4; ++nf)
          bv[nf] = *(const bf16x8*)&smB[kswz(wn * 64 + nf * 16 + lr, kb)];
        #pragma unroll
        for (int mf = 0; mf < 4; ++mf)
          #pragma unroll
          for (int nf = 0; nf < 4; ++nf)
            acc[mf][nf] = __builtin_amdgcn_mfma_f32_16x16x32_bf16(av[mf], bv[nf], acc[mf][nf], 0, 0, 0);
      }
      __syncthreads();
    }
    #pragma unroll
    for (int nf = 0; nf < 4; ++nf) {
      int cc = wn * 64 + nf * 16 + lr;
      float b1v = eb1[e * 256 + cc];
      #pragma unroll
      for (int mf = 0; mf < 4; ++mf)
        #pragma unroll
        for (int rg = 0; rg < 4; ++rg) {
          int rr = wm * 64 + mf * 16 + q4 + rg;
          hbuf[rr * HSTR + cc] = f2bf(silu_f(acc[mf][nf][rg] + b1v));
        }
    }
    __syncthreads();

    #pragma unroll
    for (int mf = 0; mf < 4; ++mf)
      #pragma unroll
      for (int nf = 0; nf < 4; ++nf)
        acc[mf][nf] = (f32x4){0.f, 0.f, 0.f, 0.f};
    for (int kt = 0; kt < 256; kt += 64) {
      #pragma unroll
      for (int c = 0; c < 4; ++c) {
        int f = c * 8192 + tid * 16;
        int r = f >> 7, ce = (f & 127) >> 1;
        gl16(W2 + (size_t)r * 256 + kt + ce, smB + ((c * 8192 + w * 1024) >> 1));
      }
      __syncthreads();
      #pragma unroll
      for (int kk = 0; kk < 2; ++kk) {
        int kbl = kk * 32 + lk;
        int kbh = kt + kbl;
        bf16x8 av[4], bv[4];
        #pragma unroll
        for (int mf = 0; mf < 4; ++mf)
          av[mf] = *(const bf16x8*)&hbuf[(wm * 64 + mf * 16 + lr) * HSTR + kbh];
        #pragma unroll
        for (int nf = 0; nf < 4; ++nf)
          bv[nf] = *(const bf16x8*)&smB[kswz(wn * 64 + nf * 16 + lr, kbl)];
        #pragma unroll
        for (int mf = 0; mf < 4; ++mf)
          #pragma unroll
          for (int nf = 0; nf < 4; ++nf)
            acc[mf][nf] = __builtin_amdgcn_mfma_f32_16x16x32_bf16(av[mf], bv[nf], acc[mf][nf], 0, 0, 0);
      }
      __syncthreads();
    }
    #pragma unroll
    for (int nf = 0; nf < 4; ++nf) {
      int cc = wn * 64 + nf * 16 + lr;
      float b2v = eb2[e * 256 + cc];
      #pragma unroll
      for (int mf = 0; mf < 4; ++mf)
        #pragma unroll
        for (int rg = 0; rg < 4; ++rg) {
          int rr = wm * 64 + mf * 16 + q4 + rg;
          float gv = sGate[rr * 8 + e];
          hbuf[rr * HSTR + cc] = f2bf(silu_f(acc[mf][nf][rg] + b2v) * gv);
        }
    }
    __syncthreads();

    for (int kt = 0; kt < 256; kt += 64) {
      #pragma unroll
      for (int c = 0; c < 4; ++c) {
        int f = c * 8192 + tid * 16;
        int r = f >> 7, ce = (f & 127) >> 1;
        gl16(W3 + (size_t)r * 256 + kt + ce, smB + ((c * 8192 + w * 1024) >> 1));
      }
      __syncthreads();
      #pragma unroll
      for (int kk = 0; kk < 2; ++kk) {
        int kbl = kk * 32 + lk;
        int kbh = kt + kbl;
        bf16x8 av[4], bv[4];
        #pragma unroll
        for (int mf = 0; mf < 4; ++mf)
          av[mf] = *(const bf16x8*)&hbuf[(wm * 64 + mf * 16 + lr) * HSTR + kbh];
        #pragma unroll
        for (int nf = 0; nf < 4; ++nf)
          bv[nf] = *(const bf16x8*)&smB[kswz(wn * 64 + nf * 16 + lr, kbl)];
        #pragma unroll
        for (int mf = 0; mf < 4; ++mf)
          #pragma unroll
          for (int nf = 0; nf < 4; ++nf)
            vacc[mf][nf] = __builtin_amdgcn_mfma_f32_16x16x32_bf16(av[mf], bv[nf], vacc[mf][nf], 0, 0, 0);
      }
      __syncthreads();
    }
  }

  #pragma unroll
  for (int mf = 0; mf < 4; ++mf)
    #pragma unroll
    for (int rg = 0; rg < 4; ++rg) {
      int rr = wm * 64 + mf * 16 + q4 + rg;
      const float* gp = &sGate[rr * 8];
      #pragma unroll
      for (int nf = 0; nf < 4; ++nf) {
        int cc = wn * 64 + nf * 16 + lr;
        float bsum = 0.f;
        #pragma unroll
        for (int ee = 0; ee < 8; ++ee) bsum += gp[ee] * sEb3[ee * 256 + cc];
        velout[(size_t)(row0 + rr) * D_EMBED + cc] = vacc[mf][nf][rg] + bsum;
      }
    }
}

extern "C" void kernel_launch(void* const* d_in, const int* in_sizes, int n_in,
                              void* d_out, int out_size, void* d_ws, size_t ws_size,
                              hipStream_t stream) {
  const float* zt   = (const float*)d_in[0];
  const float* tin  = (const float*)d_in[1];
  const float* cond = (const float*)d_in[2];
  const float* tW1  = (const float*)d_in[3];
  const float* tb1  = (const float*)d_in[4];
  const float* tW2  = (const float*)d_in[5];
  const float* tb2  = (const float*)d_in[6];
  const float* eW1  = (const float*)d_in[7];
  const float* eb1  = (const float*)d_in[8];
  const float* eW2  = (const float*)d_in[9];
  const float* eb2  = (const float*)d_in[10];
  const float* eW3  = (const float*)d_in[11];
  const float* eb3  = (const float*)d_in[12];
  const float* rW1  = (const float*)d_in[13];
  const float* rb1  = (const float*)d_in[14];
  const float* rW2  = (const float*)d_in[15];
  const float* rb2  = (const float*)d_in[16];

  char* wp = (char*)d_ws;
  ushort* xb    = (ushort*)wp; wp += (size_t)NB_ROWS * D_IN * 2;
  float*  gatef = (float*)wp;  wp += (size_t)NB_ROWS * 8 * 4;
  ushort* w1t   = (ushort*)wp; wp += (size_t)N_EXP * D_HID * D_IN * 2;
  ushort* w2t   = (ushort*)wp; wp += (size_t)N_EXP * D_HID * D_HID * 2;
  ushort* w3t   = (ushort*)wp; wp += (size_t)N_EXP * D_HID * D_EMBED * 2;
  ushort* rw1t  = (ushort*)wp; wp += (size_t)D_RHID * D_IN * 2;
  ushort* tw1t  = (ushort*)wp; wp += (size_t)128 * 128 * 2;
  ushort* tw2t  = (ushort*)wp; wp += (size_t)128 * 128 * 2;
  ushort* hg    = (ushort*)wp;
  size_t base = (size_t)(wp - (char*)d_ws);

  int CH = 0;
  for (int cand = NB_ROWS; cand >= 8192; cand >>= 1) {
    if (base + (size_t)cand * D_H1 * 2 <= ws_size) { CH = cand; break; }
  }

  float* velout  = (float*)d_out;
  float* gateout = velout + (size_t)NB_ROWS * D_EMBED;

  {
    int tot;
    tot = 128 * 128;
    prep_transpose<<<(tot + 255) / 256, 256, 0, stream>>>(tW1, tw1t, 128, 128, tot);
    prep_transpose<<<(tot + 255) / 256, 256, 0, stream>>>(tW2, tw2t, 128, 128, tot);
    tot = D_IN * D_RHID;
    prep_transpose_swz<<<(tot + 255) / 256, 256, 0, stream>>>(rW1, rw1t, D_IN, D_RHID, tot);
    tot = N_EXP * D_IN * D_HID;
    prep_transpose_swz<<<(tot + 255) / 256, 256, 0, stream>>>(eW1, w1t, D_IN, D_HID, tot);
    tot = N_EXP * D_HID * D_HID;
    prep_transpose_swz<<<(tot + 255) / 256, 256, 0, stream>>>(eW2, w2t, D_HID, D_HID, tot);
    tot = N_EXP * D_HID * D_EMBED;
    prep_transpose_swz<<<(tot + 255) / 256, 256, 0, stream>>>(eW3, w3t, D_HID, D_EMBED, tot);
  }

  time_x_kernel<<<512, 512, 0, stream>>>(zt, tin, cond, tw1t, tw2t, tb1, tb2, xb);
  router_kernel<<<512, 256, 0, stream>>>(xb, rw1t, rb1, rW2, rb2, gatef, gateout);

  if (CH > 0) {
    for (int r0 = 0; r0 < NB_ROWS; r0 += CH) {
      moe_h1_kernel<<<(CH / 128) * 8, 512, 0, stream>>>(xb, w1t, eb1, hg, r0);
      moe_h2_kernel<<<(CH / 128) * 8, 512, 0, stream>>>(hg, w2t, eb2, gatef, r0);
      moe_vel_kernel<<<CH / 64, 512, 0, stream>>>(hg, w3t, eb3, gatef, velout, r0);
    }
  } else {
    moe_fused_kernel<<<512, 512, 0, stream>>>(xb, w1t, w2t, w3t,
                                              eb1, eb2, eb3, gatef, velout);
  }
}

// Round 22
// 627.505 us; speedup vs baseline: 1.0463x; 1.0112x over previous
//
#include <hip/hip_runtime.h>

typedef __attribute__((ext_vector_type(8))) short bf16x8;
typedef __attribute__((ext_vector_type(4))) float f32x4;

#define NB_ROWS 65536
#define D_EMBED 256
#define D_HID   256
#define N_EXP   8
#define D_RHID  128
#define D_IN    640
#define D_H1    2048

#define HSTR 264   // fallback h-tile stride

static __device__ __forceinline__ ushort f2bf(float f) {
  union { float f; unsigned u; } v; v.f = f;
  unsigned r = v.u + 0x7fffu + ((v.u >> 16) & 1u);
  return (ushort)(r >> 16);
}
static __device__ __forceinline__ float bf2f(ushort h) {
  union { unsigned u; float f; } v; v.u = ((unsigned)h) << 16;
  return v.f;
}
static __device__ __forceinline__ float silu_f(float x) {
  return x / (1.0f + __expf(-x));
}

// LDS K-tile [rows][64] XOR-swizzle read index
static __device__ __forceinline__ int kswz(int r, int c) {
  return r * 64 + ((((c) >> 3) ^ (r & 7)) << 3) + ((c) & 7);
}
// global column permute (same involution, applied at matrix-store time)
static __device__ __forceinline__ int gswz(int r, int c) {
  return ((c) & ~63) | (((((c) >> 3) & 7) ^ ((r) & 7)) << 3) | ((c) & 7);
}

static __device__ __forceinline__ void gl16(const ushort* src, ushort* dst) {
  __builtin_amdgcn_global_load_lds(
      (const __attribute__((address_space(1))) void*)src,
      (__attribute__((address_space(3))) void*)dst, 16, 0, 0);
}

// ---------------- SINGLE weight-prep kernel (6 segments) ----------------
// seg layout (element counts):
//  0: tW1 128x128 plain      [0,       16384)
//  1: tW2 128x128 plain      [16384,   32768)
//  2: rW1 640x128 swz        [32768,  114688)
//  3: eW1 8x640x256 swz      [114688, 1425408)
//  4: eW2 8x256x256 swz      [1425408,1949696)
//  5: eW3 8x256x256 swz      [1949696,2473984)
__global__ void prep_all(const float* __restrict__ tW1, const float* __restrict__ tW2,
                         const float* __restrict__ rW1, const float* __restrict__ eW1,
                         const float* __restrict__ eW2, const float* __restrict__ eW3,
                         ushort* __restrict__ tw1t, ushort* __restrict__ tw2t,
                         ushort* __restrict__ rw1t, ushort* __restrict__ w1t,
                         ushort* __restrict__ w2t, ushort* __restrict__ w3t) {
  int gidx = blockIdx.x * 256 + threadIdx.x;
  if (gidx >= 2473984) return;
  const float* src; ushort* dst; int R, C; int swz; int idx;
  if (gidx < 16384)        { src = tW1; dst = tw1t; R = 128; C = 128; swz = 0; idx = gidx; }
  else if (gidx < 32768)   { src = tW2; dst = tw2t; R = 128; C = 128; swz = 0; idx = gidx - 16384; }
  else if (gidx < 114688)  { src = rW1; dst = rw1t; R = 640; C = 128; swz = 1; idx = gidx - 32768; }
  else if (gidx < 1425408) { src = eW1; dst = w1t;  R = 640; C = 256; swz = 1; idx = gidx - 114688; }
  else if (gidx < 1949696) { src = eW2; dst = w2t;  R = 256; C = 256; swz = 1; idx = gidx - 1425408; }
  else                     { src = eW3; dst = w3t;  R = 256; C = 256; swz = 1; idx = gidx - 1949696; }
  int rc = R * C;
  int m = idx / rc;
  int rem = idx - m * rc;
  int r = rem / C;       // in-dim (K)
  int c = rem - r * C;   // out-dim
  int p = swz ? ((r & ~63) + (((((r >> 3) & 7) ^ (c & 7)) << 3) | (r & 7))) : r;
  dst[m * rc + c * R + p] = f2bf(src[idx]);
}

// [128 rows][64 cols], NT=256 (router)
static __device__ __forceinline__ void glB128_256(const ushort* __restrict__ src, int ld,
                                                  int kt, ushort* dst, int tid, int w) {
  #pragma unroll
  for (int c = 0; c < 4; ++c) {
    int f = c * 4096 + tid * 16;
    int r = f >> 7, ce = (f & 127) >> 1;
    gl16(src + (size_t)r * ld + kt + ce, dst + ((c * 4096 + w * 1024) >> 1));
  }
}

// ---------------- time embedding MLP + build x (SWIZZLED x image) ----------------
__global__ __launch_bounds__(512) void time_x_kernel(
    const float* __restrict__ zt, const float* __restrict__ tin,
    const float* __restrict__ cond,
    const ushort* __restrict__ tw1t, const ushort* __restrict__ tw2t,
    const float* __restrict__ tb1, const float* __restrict__ tb2,
    ushort* __restrict__ x) {
  __shared__ __align__(16) ushort sE[128 * 136];
  __shared__ float sFreq[64];
  __shared__ float sB1[128];
  __shared__ float sB2[128];

  const int tid = threadIdx.x;
  const int row0 = blockIdx.x * 128;

  for (int ch = tid; ch < 128 * 64; ch += 512) {
    int r = ch >> 6;
    int c4 = (ch & 63) << 2;
    size_t grow = (size_t)(row0 + r);
    float4 zv = *(const float4*)&zt[grow * 256 + c4];
    ushort4 o; o.x = f2bf(zv.x); o.y = f2bf(zv.y); o.z = f2bf(zv.z); o.w = f2bf(zv.w);
    *(ushort4*)&x[grow * 640 + gswz(r, c4)] = o;
    float4 cv = *(const float4*)&cond[grow * 256 + c4];
    ushort4 o2; o2.x = f2bf(cv.x); o2.y = f2bf(cv.y); o2.z = f2bf(cv.z); o2.w = f2bf(cv.w);
    *(ushort4*)&x[grow * 640 + gswz(r, 384 + c4)] = o2;
  }

  if (tid < 64) sFreq[tid] = __expf((float)tid * (-9.210340371976184f / 63.0f));
  if (tid < 128) { sB1[tid] = tb1[tid]; sB2[tid] = tb2[tid]; }
  __syncthreads();

  {
    int r = tid >> 2;
    int qd = tid & 3;
    float tv = tin[row0 + r];
    int half = qd >> 1;
    int cbase = (qd & 1) * 32;
    ushort* er = &sE[r * 136 + half * 64 + cbase];
    #pragma unroll
    for (int c = 0; c < 32; ++c) {
      float a = tv * sFreq[cbase + c];
      float v = half ? __cosf(a) : __sinf(a);
      er[c] = f2bf(v);
    }
  }
  __syncthreads();

  const int l = tid & 63;
  const int w = tid >> 6;
  const int wm = w >> 1;
  const int wn = w & 1;
  const int lr = l & 15;
  const int lk = (l >> 4) * 8;
  const int q4 = (l >> 4) * 4;

  f32x4 acc[2][4] = {};
  #pragma unroll
  for (int kk = 0; kk < 4; ++kk) {
    int kb = kk * 32 + lk;
    bf16x8 av[2], bv[4];
    #pragma unroll
    for (int mf = 0; mf < 2; ++mf)
      av[mf] = *(const bf16x8*)&sE[(wm * 32 + mf * 16 + lr) * 136 + kb];
    #pragma unroll
    for (int nf = 0; nf < 4; ++nf)
      bv[nf] = *(const bf16x8*)&tw1t[(size_t)(wn * 64 + nf * 16 + lr) * 128 + kb];
    #pragma unroll
    for (int mf = 0; mf < 2; ++mf)
      #pragma unroll
      for (int nf = 0; nf < 4; ++nf)
        acc[mf][nf] = __builtin_amdgcn_mfma_f32_16x16x32_bf16(av[mf], bv[nf], acc[mf][nf], 0, 0, 0);
  }
  __syncthreads();
  #pragma unroll
  for (int mf = 0; mf < 2; ++mf)
    #pragma unroll
    for (int nf = 0; nf < 4; ++nf) {
      int cc = wn * 64 + nf * 16 + lr;
      #pragma unroll
      for (int rg = 0; rg < 4; ++rg) {
        int rr = wm * 32 + mf * 16 + q4 + rg;
        sE[rr * 136 + cc] = f2bf(silu_f(acc[mf][nf][rg] + sB1[cc]));
      }
    }
  __syncthreads();

  f32x4 acc2[2][4] = {};
  #pragma unroll
  for (int kk = 0; kk < 4; ++kk) {
    int kb = kk * 32 + lk;
    bf16x8 av[2], bv[4];
    #pragma unroll
    for (int mf = 0; mf < 2; ++mf)
      av[mf] = *(const bf16x8*)&sE[(wm * 32 + mf * 16 + lr) * 136 + kb];
    #pragma unroll
    for (int nf = 0; nf < 4; ++nf)
      bv[nf] = *(const bf16x8*)&tw2t[(size_t)(wn * 64 + nf * 16 + lr) * 128 + kb];
    #pragma unroll
    for (int mf = 0; mf < 2; ++mf)
      #pragma unroll
      for (int nf = 0; nf < 4; ++nf)
        acc2[mf][nf] = __builtin_amdgcn_mfma_f32_16x16x32_bf16(av[mf], bv[nf], acc2[mf][nf], 0, 0, 0);
  }
  #pragma unroll
  for (int mf = 0; mf < 2; ++mf)
    #pragma unroll
    for (int nf = 0; nf < 4; ++nf) {
      int cc = wn * 64 + nf * 16 + lr;
      #pragma unroll
      for (int rg = 0; rg < 4; ++rg) {
        int rr = wm * 32 + mf * 16 + q4 + rg;
        x[(size_t)(row0 + rr) * 640 + gswz(rr, 256 + cc)] = f2bf(acc2[mf][nf][rg] + sB2[cc]);
      }
    }
}

// ---------------- fused router (proven) ----------------
__global__ __launch_bounds__(256) void router_kernel(
    const ushort* __restrict__ xb, const ushort* __restrict__ rw1t,
    const float* __restrict__ rb1, const float* __restrict__ rW2,
    const float* __restrict__ rb2, float* __restrict__ gatef,
    float* __restrict__ gateo) {
  __shared__ __align__(16) ushort smA[128 * 64];
  __shared__ __align__(16) ushort smB[128 * 64];
  __shared__ __align__(16) ushort rhbuf[128 * 136];
  __shared__ float sW2[128 * 8];

  const int tid = threadIdx.x;
  const int row0 = blockIdx.x * 128;
  for (int i = tid; i < 1024; i += 256) sW2[i] = rW2[i];

  const int l = tid & 63;
  const int w = tid >> 6;
  const int wm = w >> 1, wn = w & 1;
  const int lr = l & 15, lk = (l >> 4) * 8, q4 = (l >> 4) * 4;
  const ushort* xrow = xb + (size_t)row0 * 640;

  f32x4 acc[4][4] = {};
  for (int kt = 0; kt < 640; kt += 64) {
    glB128_256(xrow, 640, kt, smA, tid, w);
    glB128_256(rw1t, 640, kt, smB, tid, w);
    __syncthreads();
    #pragma unroll
    for (int kk = 0; kk < 2; ++kk) {
      int kb = kk * 32 + lk;
      bf16x8 av[4], bv[4];
      #pragma unroll
      for (int mf = 0; mf < 4; ++mf)
        av[mf] = *(const bf16x8*)&smA[kswz(wm * 64 + mf * 16 + lr, kb)];
      #pragma unroll
      for (int nf = 0; nf < 4; ++nf)
        bv[nf] = *(const bf16x8*)&smB[kswz(wn * 64 + nf * 16 + lr, kb)];
      #pragma unroll
      for (int mf = 0; mf < 4; ++mf)
        #pragma unroll
        for (int nf = 0; nf < 4; ++nf)
          acc[mf][nf] = __builtin_amdgcn_mfma_f32_16x16x32_bf16(av[mf], bv[nf], acc[mf][nf], 0, 0, 0);
    }
    __syncthreads();
  }
  #pragma unroll
  for (int nf = 0; nf < 4; ++nf) {
    int cc = wn * 64 + nf * 16 + lr;
    float b1v = rb1[cc];
    #pragma unroll
    for (int mf = 0; mf < 4; ++mf)
      #pragma unroll
      for (int rg = 0; rg < 4; ++rg) {
        int rr = wm * 64 + mf * 16 + q4 + rg;
        rhbuf[rr * 136 + cc] = f2bf(silu_f(acc[mf][nf][rg] + b1v));
      }
  }
  __syncthreads();

  if (tid < 128) {
    float a[8];
    #pragma unroll
    for (int e = 0; e < 8; ++e) a[e] = rb2[e];
    #pragma unroll
    for (int i8 = 0; i8 < 16; ++i8) {
      bf16x8 hv = *(const bf16x8*)&rhbuf[tid * 136 + i8 * 8];
      #pragma unroll
      for (int j = 0; j < 8; ++j) {
        float h = bf2f((ushort)hv[j]);
        const float* wrow = &sW2[(i8 * 8 + j) * 8];
        #pragma unroll
        for (int e = 0; e < 8; ++e) a[e] += h * wrow[e];
      }
    }
    float mx = a[0];
    #pragma unroll
    for (int e = 1; e < 8; ++e) mx = fmaxf(mx, a[e]);
    float s = 0.f, ex[8];
    #pragma unroll
    for (int e = 0; e < 8; ++e) { ex[e] = __expf(a[e] - mx); s += ex[e]; }
    float inv = 1.f / s;
    size_t b = (size_t)(row0 + tid);
    #pragma unroll
    for (int e = 0; e < 8; ++e) {
      float g = ex[e] * inv;
      gatef[b * 8 + e] = g;
      gateo[b * 8 + e] = g;
    }
  }
}

// ======== split kernels (round-21 internals; natural e<->XCD mapping) ========
// K1: h1 = silu(x @ W1[e] + b1[e]) -> hg (swizzled image). e = blockIdx%8 -> one expert per XCD
__global__ __launch_bounds__(512) void moe_h1_kernel(
    const ushort* __restrict__ xb, const ushort* __restrict__ w1t,
    const float* __restrict__ eb1, ushort* __restrict__ hg, int row_base) {
  __shared__ __align__(16) ushort smA[128 * 64];
  __shared__ __align__(16) ushort smB[256 * 64];

  const int tid = threadIdx.x;
  int flat = blockIdx.x;
  const int e  = flat & 7;       // XCD-affine: W1[e] stays in one XCD's L2
  const int rb = flat >> 3;
  const int lrow0 = rb * 128;

  const int l = tid & 63;
  const int w = tid >> 6;
  const int wm = w >> 2, wn = w & 3;
  const int lr = l & 15, lk = (l >> 4) * 8, q4 = (l >> 4) * 4;

  const ushort* xrow = xb + (size_t)(row_base + lrow0) * 640;
  const ushort* W1 = w1t + (size_t)e * (256 * 640);

  const ushort* aS[2]; ushort* aD[2];
  #pragma unroll
  for (int c = 0; c < 2; ++c) {
    int f = c * 8192 + tid * 16;
    int r = f >> 7, ce = (f & 127) >> 1;
    aS[c] = xrow + (size_t)r * 640 + ce;
    aD[c] = smA + ((c * 8192 + w * 1024) >> 1);
  }
  const ushort* bS[4]; ushort* bD[4];
  #pragma unroll
  for (int c = 0; c < 4; ++c) {
    int f = c * 8192 + tid * 16;
    int r = f >> 7, ce = (f & 127) >> 1;
    bS[c] = W1 + (size_t)r * 640 + ce;
    bD[c] = smB + ((c * 8192 + w * 1024) >> 1);
  }
  int oA[2][4], oB[2][4];
  #pragma unroll
  for (int kk = 0; kk < 2; ++kk) {
    #pragma unroll
    for (int mf = 0; mf < 4; ++mf) oA[kk][mf] = kswz(wm * 64 + mf * 16 + lr, kk * 32 + lk);
    #pragma unroll
    for (int nf = 0; nf < 4; ++nf) oB[kk][nf] = kswz(wn * 64 + nf * 16 + lr, kk * 32 + lk);
  }

  f32x4 acc[4][4] = {};
  for (int kt = 0; kt < 640; kt += 64) {
    #pragma unroll
    for (int c = 0; c < 2; ++c) { gl16(aS[c], aD[c]); aS[c] += 64; }
    #pragma unroll
    for (int c = 0; c < 4; ++c) { gl16(bS[c], bD[c]); bS[c] += 64; }
    __syncthreads();
    #pragma unroll
    for (int kk = 0; kk < 2; ++kk) {
      bf16x8 av[4], bv[4];
      #pragma unroll
      for (int mf = 0; mf < 4; ++mf) av[mf] = *(const bf16x8*)&smA[oA[kk][mf]];
      #pragma unroll
      for (int nf = 0; nf < 4; ++nf) bv[nf] = *(const bf16x8*)&smB[oB[kk][nf]];
      #pragma unroll
      for (int mf = 0; mf < 4; ++mf)
        #pragma unroll
        for (int nf = 0; nf < 4; ++nf)
          acc[mf][nf] = __builtin_amdgcn_mfma_f32_16x16x32_bf16(av[mf], bv[nf], acc[mf][nf], 0, 0, 0);
    }
    __syncthreads();
  }
  #pragma unroll
  for (int nf = 0; nf < 4; ++nf) {
    int cc = wn * 64 + nf * 16 + lr;
    float b1v = eb1[e * 256 + cc];
    #pragma unroll
    for (int mf = 0; mf < 4; ++mf)
      #pragma unroll
      for (int rg = 0; rg < 4; ++rg) {
        int rr = wm * 64 + mf * 16 + q4 + rg;
        hg[(size_t)(lrow0 + rr) * D_H1 + e * 256 + gswz(rr, cc)] =
            f2bf(silu_f(acc[mf][nf][rg] + b1v));
      }
  }
}

// K2: h[:, e-slice] = gate[:,e] * silu(h @ W2[e] + b2[e]) IN-PLACE (swizzled image)
__global__ __launch_bounds__(512) void moe_h2_kernel(
    ushort* __restrict__ hg, const ushort* __restrict__ w2t,
    const float* __restrict__ eb2, const float* __restrict__ gatef, int row_base) {
  __shared__ __align__(16) ushort smA[128 * 64];
  __shared__ __align__(16) ushort smB[256 * 64];
  __shared__ float sGate[128];

  const int tid = threadIdx.x;
  int flat = blockIdx.x;
  const int e  = flat & 7;       // XCD-affine
  const int rb = flat >> 3;
  const int lrow0 = rb * 128;

  const int l = tid & 63;
  const int w = tid >> 6;
  const int wm = w >> 2, wn = w & 3;
  const int lr = l & 15, lk = (l >> 4) * 8, q4 = (l >> 4) * 4;

  if (tid < 128) sGate[tid] = gatef[(size_t)(row_base + lrow0 + tid) * 8 + e];

  ushort* hrow = hg + (size_t)lrow0 * D_H1 + e * 256;
  const ushort* W2 = w2t + (size_t)e * (256 * 256);

  const ushort* aS[2]; ushort* aD[2];
  #pragma unroll
  for (int c = 0; c < 2; ++c) {
    int f = c * 8192 + tid * 16;
    int r = f >> 7, ce = (f & 127) >> 1;
    aS[c] = hrow + (size_t)r * D_H1 + ce;
    aD[c] = smA + ((c * 8192 + w * 1024) >> 1);
  }
  const ushort* bS[4]; ushort* bD[4];
  #pragma unroll
  for (int c = 0; c < 4; ++c) {
    int f = c * 8192 + tid * 16;
    int r = f >> 7, ce = (f & 127) >> 1;
    bS[c] = W2 + (size_t)r * 256 + ce;
    bD[c] = smB + ((c * 8192 + w * 1024) >> 1);
  }
  int oA[2][4], oB[2][4];
  #pragma unroll
  for (int kk = 0; kk < 2; ++kk) {
    #pragma unroll
    for (int mf = 0; mf < 4; ++mf) oA[kk][mf] = kswz(wm * 64 + mf * 16 + lr, kk * 32 + lk);
    #pragma unroll
    for (int nf = 0; nf < 4; ++nf) oB[kk][nf] = kswz(wn * 64 + nf * 16 + lr, kk * 32 + lk);
  }

  f32x4 acc[4][4] = {};
  for (int kt = 0; kt < 256; kt += 64) {
    #pragma unroll
    for (int c = 0; c < 2; ++c) { gl16(aS[c], aD[c]); aS[c] += 64; }
    #pragma unroll
    for (int c = 0; c < 4; ++c) { gl16(bS[c], bD[c]); bS[c] += 64; }
    __syncthreads();
    #pragma unroll
    for (int kk = 0; kk < 2; ++kk) {
      bf16x8 av[4], bv[4];
      #pragma unroll
      for (int mf = 0; mf < 4; ++mf) av[mf] = *(const bf16x8*)&smA[oA[kk][mf]];
      #pragma unroll
      for (int nf = 0; nf < 4; ++nf) bv[nf] = *(const bf16x8*)&smB[oB[kk][nf]];
      #pragma unroll
      for (int mf = 0; mf < 4; ++mf)
        #pragma unroll
        for (int nf = 0; nf < 4; ++nf)
          acc[mf][nf] = __builtin_amdgcn_mfma_f32_16x16x32_bf16(av[mf], bv[nf], acc[mf][nf], 0, 0, 0);
    }
    __syncthreads();   // all hrow reads drained before in-place epilogue
  }
  #pragma unroll
  for (int nf = 0; nf < 4; ++nf) {
    int cc = wn * 64 + nf * 16 + lr;
    float b2v = eb2[e * 256 + cc];
    #pragma unroll
    for (int mf = 0; mf < 4; ++mf)
      #pragma unroll
      for (int rg = 0; rg < 4; ++rg) {
        int rr = wm * 64 + mf * 16 + q4 + rg;
        hrow[(size_t)rr * D_H1 + gswz(rr, cc)] =
            f2bf(silu_f(acc[mf][nf][rg] + b2v) * sGate[rr]);
      }
  }
}

// K3: velocity = g2 @ W3 + gate·eb3; BM=64 BN=256, 42KB LDS (round-21, proven)
__global__ __launch_bounds__(512) void moe_vel_kernel(
    const ushort* __restrict__ hg, const ushort* __restrict__ w3t,
    const float* __restrict__ eb3, const float* __restrict__ gatef,
    float* __restrict__ velout, int row_base) {
  __shared__ __align__(16) ushort smA[64 * 64];    //  8 KB
  __shared__ __align__(16) ushort smB[256 * 64];   // 32 KB
  __shared__ float sGate[64 * 8];                  //  2 KB

  const int tid = threadIdx.x;
  int nwg = gridDim.x;
  int flat = blockIdx.x;
  int sid = (flat & 7) * (nwg >> 3) + (flat >> 3);
  const int lrow0 = sid * 64;

  const int l = tid & 63;
  const int w = tid >> 6;     // 8 waves: 2(M) x 4(N), wave tile 32x64
  const int wm = w >> 2, wn = w & 3;
  const int lr = l & 15, lk = (l >> 4) * 8, q4 = (l >> 4) * 4;

  if (tid < 512) sGate[tid] = gatef[(size_t)(row_base + lrow0) * 8 + tid];

  const ushort* hrow = hg + (size_t)lrow0 * D_H1;

  const ushort* aS; ushort* aD;
  {
    int f = tid * 16;
    int r = f >> 7, ce = (f & 127) >> 1;
    aS = hrow + (size_t)r * D_H1 + ce;
    aD = smA + ((tid * 16) >> 1);
  }
  int bR[4], bC[4]; ushort* bD[4];
  #pragma unroll
  for (int c = 0; c < 4; ++c) {
    int f = c * 8192 + tid * 16;
    bR[c] = f >> 7; bC[c] = (f & 127) >> 1;
    bD[c] = smB + ((c * 8192 + w * 1024) >> 1);
  }
  int oA[2][2], oB[2][4];
  #pragma unroll
  for (int kk = 0; kk < 2; ++kk) {
    #pragma unroll
    for (int mf = 0; mf < 2; ++mf) oA[kk][mf] = kswz(wm * 32 + mf * 16 + lr, kk * 32 + lk);
    #pragma unroll
    for (int nf = 0; nf < 4; ++nf) oB[kk][nf] = kswz(wn * 64 + nf * 16 + lr, kk * 32 + lk);
  }

  f32x4 vacc[2][4] = {};
  __syncthreads();

  for (int e = 0; e < 8; ++e) {
    const ushort* bS[4];
    const ushort* W3 = w3t + (size_t)e * (256 * 256);
    #pragma unroll
    for (int c = 0; c < 4; ++c) bS[c] = W3 + (size_t)bR[c] * 256 + bC[c];
    #pragma unroll
    for (int t4 = 0; t4 < 4; ++t4) {
      gl16(aS, aD); aS += 64;
      #pragma unroll
      for (int c = 0; c < 4; ++c) { gl16(bS[c], bD[c]); bS[c] += 64; }
      __syncthreads();
      #pragma unroll
      for (int kk = 0; kk < 2; ++kk) {
        bf16x8 av[2], bv[4];
        #pragma unroll
        for (int mf = 0; mf < 2; ++mf) av[mf] = *(const bf16x8*)&smA[oA[kk][mf]];
        #pragma unroll
        for (int nf = 0; nf < 4; ++nf) bv[nf] = *(const bf16x8*)&smB[oB[kk][nf]];
        #pragma unroll
        for (int mf = 0; mf < 2; ++mf)
          #pragma unroll
          for (int nf = 0; nf < 4; ++nf)
            vacc[mf][nf] = __builtin_amdgcn_mfma_f32_16x16x32_bf16(av[mf], bv[nf], vacc[mf][nf], 0, 0, 0);
      }
      __syncthreads();
    }
  }

  float* eL = (float*)smB;
  for (int i = tid; i < 2048; i += 512) eL[i] = eb3[i];
  __syncthreads();
  #pragma unroll
  for (int mf = 0; mf < 2; ++mf)
    #pragma unroll
    for (int rg = 0; rg < 4; ++rg) {
      int rr = wm * 32 + mf * 16 + q4 + rg;
      const float* gp = &sGate[rr * 8];
      #pragma unroll
      for (int nf = 0; nf < 4; ++nf) {
        int cc = wn * 64 + nf * 16 + lr;
        float bsum = 0.f;
        #pragma unroll
        for (int ee = 0; ee < 8; ++ee) bsum += gp[ee] * eL[ee * 256 + cc];
        velout[(size_t)(row_base + lrow0 + rr) * D_EMBED + cc] = vacc[mf][nf][rg] + bsum;
      }
    }
}

// ---- FALLBACK (round-20/21, passed): fused moe; gload_lds + kswz; hbuf plain ----
__global__ __launch_bounds__(512) void moe_fused_kernel(
    const ushort* __restrict__ xb, const ushort* __restrict__ w1t,
    const ushort* __restrict__ w2t, const ushort* __restrict__ w3t,
    const float* __restrict__ eb1, const float* __restrict__ eb2,
    const float* __restrict__ eb3, const float* __restrict__ gatef,
    float* __restrict__ velout) {
  __shared__ __align__(16) ushort smA[128 * 64];
  __shared__ __align__(16) ushort smB[256 * 64];
  __shared__ __align__(16) ushort hbuf[128 * HSTR];
  __shared__ float sGate[128 * 8];
  __shared__ float sEb3[8 * 256];

  const int tid = threadIdx.x;
  const int row0 = blockIdx.x * 128;
  const int l = tid & 63;
  const int w = tid >> 6;
  const int wm = w >> 2, wn = w & 3;
  const int lr = l & 15, lk = (l >> 4) * 8, q4 = (l >> 4) * 4;

  for (int i = tid; i < 1024; i += 512) sGate[i] = gatef[(size_t)row0 * 8 + i];
  for (int i = tid; i < 2048; i += 512) sEb3[i] = eb3[i];

  const ushort* xrow = xb + (size_t)row0 * 640;
  f32x4 vacc[4][4] = {};
  __syncthreads();

  for (int e = 0; e < 8; ++e) {
    const ushort* W1 = w1t + (size_t)e * (256 * 640);
    const ushort* W2 = w2t + (size_t)e * (256 * 256);
    const ushort* W3 = w3t + (size_t)e * (256 * 256);

    f32x4 acc[4][4] = {};
    for (int kt = 0; kt < 640; kt += 64) {
      #pragma unroll
      for (int c = 0; c < 2; ++c) {
        int f = c * 8192 + tid * 16;
        int r = f >> 7, ce = (f & 127) >> 1;
        gl16(xrow + (size_t)r * 640 + kt + ce, smA + ((c * 8192 + w * 1024) >> 1));
      }
      #pragma unroll
      for (int c = 0; c < 4; ++c) {
        int f = c * 8192 + tid * 16;
        int r = f >> 7, ce = (f & 127) >> 1;
        gl16(W1 + (size_t)r * 640 + kt + ce, smB + ((c * 8192 + w * 1024) >> 1));
      }
      __syncthreads();
      #pragma unroll
      for (int kk = 0; kk < 2; ++kk) {
        int kb = kk * 32 + lk;
        bf16x8 av[4], bv[4];
        #pragma unroll
        for (int mf = 0; mf < 4; ++mf)
          av[mf] = *(const bf16x8*)&smA[kswz(wm * 64 + mf * 16 + lr, kb)];
        #pragma unroll
        for (int nf = 0; nf < 4; ++nf)
          bv[nf] = *(const bf16x8*)&smB[kswz(wn * 64 + nf * 16 + lr, kb)];
        #pragma unroll
        for (int mf = 0; mf < 4; ++mf)
          #pragma unroll
          for (int nf = 0; nf < 4; ++nf)
            acc[mf][nf] = __builtin_amdgcn_mfma_f32_16x16x32_bf16(av[mf], bv[nf], acc[mf][nf], 0, 0, 0);
      }
      __syncthreads();
    }
    #pragma unroll
    for (int nf = 0; nf < 4; ++nf) {
      int cc = wn * 64 + nf * 16 + lr;
      float b1v = eb1[e * 256 + cc];
      #pragma unroll
      for (int mf = 0; mf < 4; ++mf)
        #pragma unroll
        for (int rg = 0; rg < 4; ++rg) {
          int rr = wm * 64 + mf * 16 + q4 + rg;
          hbuf[rr * HSTR + cc] = f2bf(silu_f(acc[mf][nf][rg] + b1v));
        }
    }
    __syncthreads();

    #pragma unroll
    for (int mf = 0; mf < 4; ++mf)
      #pragma unroll
      for (int nf = 0; nf < 4; ++nf)
        acc[mf][nf] = (f32x4){0.f, 0.f, 0.f, 0.f};
    for (int kt = 0; kt < 256; kt += 64) {
      #pragma unroll
      for (int c = 0; c < 4; ++c) {
        int f = c * 8192 + tid * 16;
        int r = f >> 7, ce = (f & 127) >> 1;
        gl16(W2 + (size_t)r * 256 + kt + ce, smB + ((c * 8192 + w * 1024) >> 1));
      }
      __syncthreads();
      #pragma unroll
      for (int kk = 0; kk < 2; ++kk) {
        int kbl = kk * 32 + lk;
        int kbh = kt + kbl;
        bf16x8 av[4], bv[4];
        #pragma unroll
        for (int mf = 0; mf < 4; ++mf)
          av[mf] = *(const bf16x8*)&hbuf[(wm * 64 + mf * 16 + lr) * HSTR + kbh];
        #pragma unroll
        for (int nf = 0; nf < 4; ++nf)
          bv[nf] = *(const bf16x8*)&smB[kswz(wn * 64 + nf * 16 + lr, kbl)];
        #pragma unroll
        for (int mf = 0; mf < 4; ++mf)
          #pragma unroll
          for (int nf = 0; nf < 4; ++nf)
            acc[mf][nf] = __builtin_amdgcn_mfma_f32_16x16x32_bf16(av[mf], bv[nf], acc[mf][nf], 0, 0, 0);
      }
      __syncthreads();
    }
    #pragma unroll
    for (int nf = 0; nf < 4; ++nf) {
      int cc = wn * 64 + nf * 16 + lr;
      float b2v = eb2[e * 256 + cc];
      #pragma unroll
      for (int mf = 0; mf < 4; ++mf)
        #pragma unroll
        for (int rg = 0; rg < 4; ++rg) {
          int rr = wm * 64 + mf * 16 + q4 + rg;
          float gv = sGate[rr * 8 + e];
          hbuf[rr * HSTR + cc] = f2bf(silu_f(acc[mf][nf][rg] + b2v) * gv);
        }
    }
    __syncthreads();

    for (int kt = 0; kt < 256; kt += 64) {
      #pragma unroll
      for (int c = 0; c < 4; ++c) {
        int f = c * 8192 + tid * 16;
        int r = f >> 7, ce = (f & 127) >> 1;
        gl16(W3 + (size_t)r * 256 + kt + ce, smB + ((c * 8192 + w * 1024) >> 1));
      }
      __syncthreads();
      #pragma unroll
      for (int kk = 0; kk < 2; ++kk) {
        int kbl = kk * 32 + lk;
        int kbh = kt + kbl;
        bf16x8 av[4], bv[4];
        #pragma unroll
        for (int mf = 0; mf < 4; ++mf)
          av[mf] = *(const bf16x8*)&hbuf[(wm * 64 + mf * 16 + lr) * HSTR + kbh];
        #pragma unroll
        for (int nf = 0; nf < 4; ++nf)
          bv[nf] = *(const bf16x8*)&smB[kswz(wn * 64 + nf * 16 + lr, kbl)];
        #pragma unroll
        for (int mf = 0; mf < 4; ++mf)
          #pragma unroll
          for (int nf = 0; nf < 4; ++nf)
            vacc[mf][nf] = __builtin_amdgcn_mfma_f32_16x16x32_bf16(av[mf], bv[nf], vacc[mf][nf], 0, 0, 0);
      }
      __syncthreads();
    }
  }

  #pragma unroll
  for (int mf = 0; mf < 4; ++mf)
    #pragma unroll
    for (int rg = 0; rg < 4; ++rg) {
      int rr = wm * 64 + mf * 16 + q4 + rg;
      const float* gp = &sGate[rr * 8];
      #pragma unroll
      for (int nf = 0; nf < 4; ++nf) {
        int cc = wn * 64 + nf * 16 + lr;
        float bsum = 0.f;
        #pragma unroll
        for (int ee = 0; ee < 8; ++ee) bsum += gp[ee] * sEb3[ee * 256 + cc];
        velout[(size_t)(row0 + rr) * D_EMBED + cc] = vacc[mf][nf][rg] + bsum;
      }
    }
}

extern "C" void kernel_launch(void* const* d_in, const int* in_sizes, int n_in,
                              void* d_out, int out_size, void* d_ws, size_t ws_size,
                              hipStream_t stream) {
  const float* zt   = (const float*)d_in[0];
  const float* tin  = (const float*)d_in[1];
  const float* cond = (const float*)d_in[2];
  const float* tW1  = (const float*)d_in[3];
  const float* tb1  = (const float*)d_in[4];
  const float* tW2  = (const float*)d_in[5];
  const float* tb2  = (const float*)d_in[6];
  const float* eW1  = (const float*)d_in[7];
  const float* eb1  = (const float*)d_in[8];
  const float* eW2  = (const float*)d_in[9];
  const float* eb2  = (const float*)d_in[10];
  const float* eW3  = (const float*)d_in[11];
  const float* eb3  = (const float*)d_in[12];
  const float* rW1  = (const float*)d_in[13];
  const float* rb1  = (const float*)d_in[14];
  const float* rW2  = (const float*)d_in[15];
  const float* rb2  = (const float*)d_in[16];

  char* wp = (char*)d_ws;
  ushort* xb    = (ushort*)wp; wp += (size_t)NB_ROWS * D_IN * 2;
  float*  gatef = (float*)wp;  wp += (size_t)NB_ROWS * 8 * 4;
  ushort* w1t   = (ushort*)wp; wp += (size_t)N_EXP * D_HID * D_IN * 2;
  ushort* w2t   = (ushort*)wp; wp += (size_t)N_EXP * D_HID * D_HID * 2;
  ushort* w3t   = (ushort*)wp; wp += (size_t)N_EXP * D_HID * D_EMBED * 2;
  ushort* rw1t  = (ushort*)wp; wp += (size_t)D_RHID * D_IN * 2;
  ushort* tw1t  = (ushort*)wp; wp += (size_t)128 * 128 * 2;
  ushort* tw2t  = (ushort*)wp; wp += (size_t)128 * 128 * 2;
  ushort* hg    = (ushort*)wp;
  size_t base = (size_t)(wp - (char*)d_ws);

  int CH = 0;
  for (int cand = NB_ROWS; cand >= 8192; cand >>= 1) {
    if (base + (size_t)cand * D_H1 * 2 <= ws_size) { CH = cand; break; }
  }

  float* velout  = (float*)d_out;
  float* gateout = velout + (size_t)NB_ROWS * D_EMBED;

  prep_all<<<(2473984 + 255) / 256, 256, 0, stream>>>(
      tW1, tW2, rW1, eW1, eW2, eW3, tw1t, tw2t, rw1t, w1t, w2t, w3t);

  time_x_kernel<<<512, 512, 0, stream>>>(zt, tin, cond, tw1t, tw2t, tb1, tb2, xb);
  router_kernel<<<512, 256, 0, stream>>>(xb, rw1t, rb1, rW2, rb2, gatef, gateout);

  if (CH > 0) {
    for (int r0 = 0; r0 < NB_ROWS; r0 += CH) {
      moe_h1_kernel<<<(CH / 128) * 8, 512, 0, stream>>>(xb, w1t, eb1, hg, r0);
      moe_h2_kernel<<<(CH / 128) * 8, 512, 0, stream>>>(hg, w2t, eb2, gatef, r0);
      moe_vel_kernel<<<CH / 64, 512, 0, stream>>>(hg, w3t, eb3, gatef, velout, r0);
    }
  } else {
    moe_fused_kernel<<<512, 512, 0, stream>>>(xb, w1t, w2t, w3t,
                                              eb1, eb2, eb3, gatef, velout);
  }
}

// Round 23
// 620.761 us; speedup vs baseline: 1.0577x; 1.0109x over previous
//
#include <hip/hip_runtime.h>

typedef __attribute__((ext_vector_type(8))) short bf16x8;
typedef __attribute__((ext_vector_type(4))) float f32x4;

#define NB_ROWS 65536
#define D_EMBED 256
#define D_HID   256
#define N_EXP   8
#define D_RHID  128
#define D_IN    640
#define D_H1    2048

#define HSTR 264   // fallback h-tile stride

static __device__ __forceinline__ ushort f2bf(float f) {
  union { float f; unsigned u; } v; v.f = f;
  unsigned r = v.u + 0x7fffu + ((v.u >> 16) & 1u);
  return (ushort)(r >> 16);
}
static __device__ __forceinline__ float bf2f(ushort h) {
  union { unsigned u; float f; } v; v.u = ((unsigned)h) << 16;
  return v.f;
}
static __device__ __forceinline__ float silu_f(float x) {
  return x / (1.0f + __expf(-x));
}

// LDS K-tile [rows][64] XOR-swizzle read index
static __device__ __forceinline__ int kswz(int r, int c) {
  return r * 64 + ((((c) >> 3) ^ (r & 7)) << 3) + ((c) & 7);
}
// global column permute (same involution, applied at matrix-store time)
static __device__ __forceinline__ int gswz(int r, int c) {
  return ((c) & ~63) | (((((c) >> 3) & 7) ^ ((r) & 7)) << 3) | ((c) & 7);
}

static __device__ __forceinline__ void gl16(const ushort* src, ushort* dst) {
  __builtin_amdgcn_global_load_lds(
      (const __attribute__((address_space(1))) void*)src,
      (__attribute__((address_space(3))) void*)dst, 16, 0, 0);
}

// ---------------- SINGLE weight-prep kernel (6 segments) ----------------
__global__ void prep_all(const float* __restrict__ tW1, const float* __restrict__ tW2,
                         const float* __restrict__ rW1, const float* __restrict__ eW1,
                         const float* __restrict__ eW2, const float* __restrict__ eW3,
                         ushort* __restrict__ tw1t, ushort* __restrict__ tw2t,
                         ushort* __restrict__ rw1t, ushort* __restrict__ w1t,
                         ushort* __restrict__ w2t, ushort* __restrict__ w3t) {
  int gidx = blockIdx.x * 256 + threadIdx.x;
  if (gidx >= 2473984) return;
  const float* src; ushort* dst; int R, C; int swz; int idx;
  if (gidx < 16384)        { src = tW1; dst = tw1t; R = 128; C = 128; swz = 0; idx = gidx; }
  else if (gidx < 32768)   { src = tW2; dst = tw2t; R = 128; C = 128; swz = 0; idx = gidx - 16384; }
  else if (gidx < 114688)  { src = rW1; dst = rw1t; R = 640; C = 128; swz = 1; idx = gidx - 32768; }
  else if (gidx < 1425408) { src = eW1; dst = w1t;  R = 640; C = 256; swz = 1; idx = gidx - 114688; }
  else if (gidx < 1949696) { src = eW2; dst = w2t;  R = 256; C = 256; swz = 1; idx = gidx - 1425408; }
  else                     { src = eW3; dst = w3t;  R = 256; C = 256; swz = 1; idx = gidx - 1949696; }
  int rc = R * C;
  int m = idx / rc;
  int rem = idx - m * rc;
  int r = rem / C;       // in-dim (K)
  int c = rem - r * C;   // out-dim
  int p = swz ? ((r & ~63) + (((((r >> 3) & 7) ^ (c & 7)) << 3) | (r & 7))) : r;
  dst[m * rc + c * R + p] = f2bf(src[idx]);
}

// [128 rows][64 cols], NT=256 (router)
static __device__ __forceinline__ void glB128_256(const ushort* __restrict__ src, int ld,
                                                  int kt, ushort* dst, int tid, int w) {
  #pragma unroll
  for (int c = 0; c < 4; ++c) {
    int f = c * 4096 + tid * 16;
    int r = f >> 7, ce = (f & 127) >> 1;
    gl16(src + (size_t)r * ld + kt + ce, dst + ((c * 4096 + w * 1024) >> 1));
  }
}

// ---------------- time embedding MLP + build x (SWIZZLED x image) ----------------
__global__ __launch_bounds__(512) void time_x_kernel(
    const float* __restrict__ zt, const float* __restrict__ tin,
    const float* __restrict__ cond,
    const ushort* __restrict__ tw1t, const ushort* __restrict__ tw2t,
    const float* __restrict__ tb1, const float* __restrict__ tb2,
    ushort* __restrict__ x) {
  __shared__ __align__(16) ushort sE[128 * 136];
  __shared__ float sFreq[64];
  __shared__ float sB1[128];
  __shared__ float sB2[128];

  const int tid = threadIdx.x;
  const int row0 = blockIdx.x * 128;

  for (int ch = tid; ch < 128 * 64; ch += 512) {
    int r = ch >> 6;
    int c4 = (ch & 63) << 2;
    size_t grow = (size_t)(row0 + r);
    float4 zv = *(const float4*)&zt[grow * 256 + c4];
    ushort4 o; o.x = f2bf(zv.x); o.y = f2bf(zv.y); o.z = f2bf(zv.z); o.w = f2bf(zv.w);
    *(ushort4*)&x[grow * 640 + gswz(r, c4)] = o;
    float4 cv = *(const float4*)&cond[grow * 256 + c4];
    ushort4 o2; o2.x = f2bf(cv.x); o2.y = f2bf(cv.y); o2.z = f2bf(cv.z); o2.w = f2bf(cv.w);
    *(ushort4*)&x[grow * 640 + gswz(r, 384 + c4)] = o2;
  }

  if (tid < 64) sFreq[tid] = __expf((float)tid * (-9.210340371976184f / 63.0f));
  if (tid < 128) { sB1[tid] = tb1[tid]; sB2[tid] = tb2[tid]; }
  __syncthreads();

  {
    int r = tid >> 2;
    int qd = tid & 3;
    float tv = tin[row0 + r];
    int half = qd >> 1;
    int cbase = (qd & 1) * 32;
    ushort* er = &sE[r * 136 + half * 64 + cbase];
    #pragma unroll
    for (int c = 0; c < 32; ++c) {
      float a = tv * sFreq[cbase + c];
      float v = half ? __cosf(a) : __sinf(a);
      er[c] = f2bf(v);
    }
  }
  __syncthreads();

  const int l = tid & 63;
  const int w = tid >> 6;
  const int wm = w >> 1;
  const int wn = w & 1;
  const int lr = l & 15;
  const int lk = (l >> 4) * 8;
  const int q4 = (l >> 4) * 4;

  f32x4 acc[2][4] = {};
  #pragma unroll
  for (int kk = 0; kk < 4; ++kk) {
    int kb = kk * 32 + lk;
    bf16x8 av[2], bv[4];
    #pragma unroll
    for (int mf = 0; mf < 2; ++mf)
      av[mf] = *(const bf16x8*)&sE[(wm * 32 + mf * 16 + lr) * 136 + kb];
    #pragma unroll
    for (int nf = 0; nf < 4; ++nf)
      bv[nf] = *(const bf16x8*)&tw1t[(size_t)(wn * 64 + nf * 16 + lr) * 128 + kb];
    #pragma unroll
    for (int mf = 0; mf < 2; ++mf)
      #pragma unroll
      for (int nf = 0; nf < 4; ++nf)
        acc[mf][nf] = __builtin_amdgcn_mfma_f32_16x16x32_bf16(av[mf], bv[nf], acc[mf][nf], 0, 0, 0);
  }
  __syncthreads();
  #pragma unroll
  for (int mf = 0; mf < 2; ++mf)
    #pragma unroll
    for (int nf = 0; nf < 4; ++nf) {
      int cc = wn * 64 + nf * 16 + lr;
      #pragma unroll
      for (int rg = 0; rg < 4; ++rg) {
        int rr = wm * 32 + mf * 16 + q4 + rg;
        sE[rr * 136 + cc] = f2bf(silu_f(acc[mf][nf][rg] + sB1[cc]));
      }
    }
  __syncthreads();

  f32x4 acc2[2][4] = {};
  #pragma unroll
  for (int kk = 0; kk < 4; ++kk) {
    int kb = kk * 32 + lk;
    bf16x8 av[2], bv[4];
    #pragma unroll
    for (int mf = 0; mf < 2; ++mf)
      av[mf] = *(const bf16x8*)&sE[(wm * 32 + mf * 16 + lr) * 136 + kb];
    #pragma unroll
    for (int nf = 0; nf < 4; ++nf)
      bv[nf] = *(const bf16x8*)&tw2t[(size_t)(wn * 64 + nf * 16 + lr) * 128 + kb];
    #pragma unroll
    for (int mf = 0; mf < 2; ++mf)
      #pragma unroll
      for (int nf = 0; nf < 4; ++nf)
        acc2[mf][nf] = __builtin_amdgcn_mfma_f32_16x16x32_bf16(av[mf], bv[nf], acc2[mf][nf], 0, 0, 0);
  }
  #pragma unroll
  for (int mf = 0; mf < 2; ++mf)
    #pragma unroll
    for (int nf = 0; nf < 4; ++nf) {
      int cc = wn * 64 + nf * 16 + lr;
      #pragma unroll
      for (int rg = 0; rg < 4; ++rg) {
        int rr = wm * 32 + mf * 16 + q4 + rg;
        x[(size_t)(row0 + rr) * 640 + gswz(rr, 256 + cc)] = f2bf(acc2[mf][nf][rg] + sB2[cc]);
      }
    }
}

// ---------------- fused router (proven) ----------------
__global__ __launch_bounds__(256) void router_kernel(
    const ushort* __restrict__ xb, const ushort* __restrict__ rw1t,
    const float* __restrict__ rb1, const float* __restrict__ rW2,
    const float* __restrict__ rb2, float* __restrict__ gatef,
    float* __restrict__ gateo) {
  __shared__ __align__(16) ushort smA[128 * 64];
  __shared__ __align__(16) ushort smB[128 * 64];
  __shared__ __align__(16) ushort rhbuf[128 * 136];
  __shared__ float sW2[128 * 8];

  const int tid = threadIdx.x;
  const int row0 = blockIdx.x * 128;
  for (int i = tid; i < 1024; i += 256) sW2[i] = rW2[i];

  const int l = tid & 63;
  const int w = tid >> 6;
  const int wm = w >> 1, wn = w & 1;
  const int lr = l & 15, lk = (l >> 4) * 8, q4 = (l >> 4) * 4;
  const ushort* xrow = xb + (size_t)row0 * 640;

  f32x4 acc[4][4] = {};
  for (int kt = 0; kt < 640; kt += 64) {
    glB128_256(xrow, 640, kt, smA, tid, w);
    glB128_256(rw1t, 640, kt, smB, tid, w);
    __syncthreads();
    #pragma unroll
    for (int kk = 0; kk < 2; ++kk) {
      int kb = kk * 32 + lk;
      bf16x8 av[4], bv[4];
      #pragma unroll
      for (int mf = 0; mf < 4; ++mf)
        av[mf] = *(const bf16x8*)&smA[kswz(wm * 64 + mf * 16 + lr, kb)];
      #pragma unroll
      for (int nf = 0; nf < 4; ++nf)
        bv[nf] = *(const bf16x8*)&smB[kswz(wn * 64 + nf * 16 + lr, kb)];
      #pragma unroll
      for (int mf = 0; mf < 4; ++mf)
        #pragma unroll
        for (int nf = 0; nf < 4; ++nf)
          acc[mf][nf] = __builtin_amdgcn_mfma_f32_16x16x32_bf16(av[mf], bv[nf], acc[mf][nf], 0, 0, 0);
    }
    __syncthreads();
  }
  #pragma unroll
  for (int nf = 0; nf < 4; ++nf) {
    int cc = wn * 64 + nf * 16 + lr;
    float b1v = rb1[cc];
    #pragma unroll
    for (int mf = 0; mf < 4; ++mf)
      #pragma unroll
      for (int rg = 0; rg < 4; ++rg) {
        int rr = wm * 64 + mf * 16 + q4 + rg;
        rhbuf[rr * 136 + cc] = f2bf(silu_f(acc[mf][nf][rg] + b1v));
      }
  }
  __syncthreads();

  if (tid < 128) {
    float a[8];
    #pragma unroll
    for (int e = 0; e < 8; ++e) a[e] = rb2[e];
    #pragma unroll
    for (int i8 = 0; i8 < 16; ++i8) {
      bf16x8 hv = *(const bf16x8*)&rhbuf[tid * 136 + i8 * 8];
      #pragma unroll
      for (int j = 0; j < 8; ++j) {
        float h = bf2f((ushort)hv[j]);
        const float* wrow = &sW2[(i8 * 8 + j) * 8];
        #pragma unroll
        for (int e = 0; e < 8; ++e) a[e] += h * wrow[e];
      }
    }
    float mx = a[0];
    #pragma unroll
    for (int e = 1; e < 8; ++e) mx = fmaxf(mx, a[e]);
    float s = 0.f, ex[8];
    #pragma unroll
    for (int e = 0; e < 8; ++e) { ex[e] = __expf(a[e] - mx); s += ex[e]; }
    float inv = 1.f / s;
    size_t b = (size_t)(row0 + tid);
    #pragma unroll
    for (int e = 0; e < 8; ++e) {
      float g = ex[e] * inv;
      gatef[b * 8 + e] = g;
      gateo[b * 8 + e] = g;
    }
  }
}

// ======== split kernels (round-21 XCD swizzle: same-rb blocks on one XCD) ========
// K1: h1 = silu(x @ W1[e] + b1[e]) -> hg (swizzled image)
__global__ __launch_bounds__(512) void moe_h1_kernel(
    const ushort* __restrict__ xb, const ushort* __restrict__ w1t,
    const float* __restrict__ eb1, ushort* __restrict__ hg, int row_base) {
  __shared__ __align__(16) ushort smA[128 * 64];
  __shared__ __align__(16) ushort smB[256 * 64];

  const int tid = threadIdx.x;
  int nwg = gridDim.x;
  int flat = blockIdx.x;
  int sid = (flat & 7) * (nwg >> 3) + (flat >> 3);   // same-rb group -> one XCD (x reuse)
  const int rb = sid >> 3;
  const int e  = sid & 7;
  const int lrow0 = rb * 128;

  const int l = tid & 63;
  const int w = tid >> 6;
  const int wm = w >> 2, wn = w & 3;
  const int lr = l & 15, lk = (l >> 4) * 8, q4 = (l >> 4) * 4;

  const ushort* xrow = xb + (size_t)(row_base + lrow0) * 640;
  const ushort* W1 = w1t + (size_t)e * (256 * 640);

  const ushort* aS[2]; ushort* aD[2];
  #pragma unroll
  for (int c = 0; c < 2; ++c) {
    int f = c * 8192 + tid * 16;
    int r = f >> 7, ce = (f & 127) >> 1;
    aS[c] = xrow + (size_t)r * 640 + ce;
    aD[c] = smA + ((c * 8192 + w * 1024) >> 1);
  }
  const ushort* bS[4]; ushort* bD[4];
  #pragma unroll
  for (int c = 0; c < 4; ++c) {
    int f = c * 8192 + tid * 16;
    int r = f >> 7, ce = (f & 127) >> 1;
    bS[c] = W1 + (size_t)r * 640 + ce;
    bD[c] = smB + ((c * 8192 + w * 1024) >> 1);
  }
  int oA[2][4], oB[2][4];
  #pragma unroll
  for (int kk = 0; kk < 2; ++kk) {
    #pragma unroll
    for (int mf = 0; mf < 4; ++mf) oA[kk][mf] = kswz(wm * 64 + mf * 16 + lr, kk * 32 + lk);
    #pragma unroll
    for (int nf = 0; nf < 4; ++nf) oB[kk][nf] = kswz(wn * 64 + nf * 16 + lr, kk * 32 + lk);
  }

  f32x4 acc[4][4] = {};
  for (int kt = 0; kt < 640; kt += 64) {
    #pragma unroll
    for (int c = 0; c < 2; ++c) { gl16(aS[c], aD[c]); aS[c] += 64; }
    #pragma unroll
    for (int c = 0; c < 4; ++c) { gl16(bS[c], bD[c]); bS[c] += 64; }
    __syncthreads();
    #pragma unroll
    for (int kk = 0; kk < 2; ++kk) {
      bf16x8 av[4], bv[4];
      #pragma unroll
      for (int mf = 0; mf < 4; ++mf) av[mf] = *(const bf16x8*)&smA[oA[kk][mf]];
      #pragma unroll
      for (int nf = 0; nf < 4; ++nf) bv[nf] = *(const bf16x8*)&smB[oB[kk][nf]];
      #pragma unroll
      for (int mf = 0; mf < 4; ++mf)
        #pragma unroll
        for (int nf = 0; nf < 4; ++nf)
          acc[mf][nf] = __builtin_amdgcn_mfma_f32_16x16x32_bf16(av[mf], bv[nf], acc[mf][nf], 0, 0, 0);
    }
    __syncthreads();
  }
  #pragma unroll
  for (int nf = 0; nf < 4; ++nf) {
    int cc = wn * 64 + nf * 16 + lr;
    float b1v = eb1[e * 256 + cc];
    #pragma unroll
    for (int mf = 0; mf < 4; ++mf)
      #pragma unroll
      for (int rg = 0; rg < 4; ++rg) {
        int rr = wm * 64 + mf * 16 + q4 + rg;
        hg[(size_t)(lrow0 + rr) * D_H1 + e * 256 + gswz(rr, cc)] =
            f2bf(silu_f(acc[mf][nf][rg] + b1v));
      }
  }
}

// K2: h[:, e-slice] = gate[:,e] * silu(h @ W2[e] + b2[e]) IN-PLACE (swizzled image)
__global__ __launch_bounds__(512) void moe_h2_kernel(
    ushort* __restrict__ hg, const ushort* __restrict__ w2t,
    const float* __restrict__ eb2, const float* __restrict__ gatef, int row_base) {
  __shared__ __align__(16) ushort smA[128 * 64];
  __shared__ __align__(16) ushort smB[256 * 64];
  __shared__ float sGate[128];

  const int tid = threadIdx.x;
  int nwg = gridDim.x;
  int flat = blockIdx.x;
  int sid = (flat & 7) * (nwg >> 3) + (flat >> 3);
  const int rb = sid >> 3;
  const int e  = sid & 7;
  const int lrow0 = rb * 128;

  const int l = tid & 63;
  const int w = tid >> 6;
  const int wm = w >> 2, wn = w & 3;
  const int lr = l & 15, lk = (l >> 4) * 8, q4 = (l >> 4) * 4;

  if (tid < 128) sGate[tid] = gatef[(size_t)(row_base + lrow0 + tid) * 8 + e];

  ushort* hrow = hg + (size_t)lrow0 * D_H1 + e * 256;
  const ushort* W2 = w2t + (size_t)e * (256 * 256);

  const ushort* aS[2]; ushort* aD[2];
  #pragma unroll
  for (int c = 0; c < 2; ++c) {
    int f = c * 8192 + tid * 16;
    int r = f >> 7, ce = (f & 127) >> 1;
    aS[c] = hrow + (size_t)r * D_H1 + ce;
    aD[c] = smA + ((c * 8192 + w * 1024) >> 1);
  }
  const ushort* bS[4]; ushort* bD[4];
  #pragma unroll
  for (int c = 0; c < 4; ++c) {
    int f = c * 8192 + tid * 16;
    int r = f >> 7, ce = (f & 127) >> 1;
    bS[c] = W2 + (size_t)r * 256 + ce;
    bD[c] = smB + ((c * 8192 + w * 1024) >> 1);
  }
  int oA[2][4], oB[2][4];
  #pragma unroll
  for (int kk = 0; kk < 2; ++kk) {
    #pragma unroll
    for (int mf = 0; mf < 4; ++mf) oA[kk][mf] = kswz(wm * 64 + mf * 16 + lr, kk * 32 + lk);
    #pragma unroll
    for (int nf = 0; nf < 4; ++nf) oB[kk][nf] = kswz(wn * 64 + nf * 16 + lr, kk * 32 + lk);
  }

  f32x4 acc[4][4] = {};
  for (int kt = 0; kt < 256; kt += 64) {
    #pragma unroll
    for (int c = 0; c < 2; ++c) { gl16(aS[c], aD[c]); aS[c] += 64; }
    #pragma unroll
    for (int c = 0; c < 4; ++c) { gl16(bS[c], bD[c]); bS[c] += 64; }
    __syncthreads();
    #pragma unroll
    for (int kk = 0; kk < 2; ++kk) {
      bf16x8 av[4], bv[4];
      #pragma unroll
      for (int mf = 0; mf < 4; ++mf) av[mf] = *(const bf16x8*)&smA[oA[kk][mf]];
      #pragma unroll
      for (int nf = 0; nf < 4; ++nf) bv[nf] = *(const bf16x8*)&smB[oB[kk][nf]];
      #pragma unroll
      for (int mf = 0; mf < 4; ++mf)
        #pragma unroll
        for (int nf = 0; nf < 4; ++nf)
          acc[mf][nf] = __builtin_amdgcn_mfma_f32_16x16x32_bf16(av[mf], bv[nf], acc[mf][nf], 0, 0, 0);
    }
    __syncthreads();   // all hrow reads drained before in-place epilogue
  }
  #pragma unroll
  for (int nf = 0; nf < 4; ++nf) {
    int cc = wn * 64 + nf * 16 + lr;
    float b2v = eb2[e * 256 + cc];
    #pragma unroll
    for (int mf = 0; mf < 4; ++mf)
      #pragma unroll
      for (int rg = 0; rg < 4; ++rg) {
        int rr = wm * 64 + mf * 16 + q4 + rg;
        hrow[(size_t)rr * D_H1 + gswz(rr, cc)] =
            f2bf(silu_f(acc[mf][nf][rg] + b2v) * sGate[rr]);
      }
  }
}

// K3: velocity = g2 @ W3 + gate·eb3; BM=64 BN=256, 42KB LDS (round-21, proven)
__global__ __launch_bounds__(512) void moe_vel_kernel(
    const ushort* __restrict__ hg, const ushort* __restrict__ w3t,
    const float* __restrict__ eb3, const float* __restrict__ gatef,
    float* __restrict__ velout, int row_base) {
  __shared__ __align__(16) ushort smA[64 * 64];    //  8 KB
  __shared__ __align__(16) ushort smB[256 * 64];   // 32 KB
  __shared__ float sGate[64 * 8];                  //  2 KB

  const int tid = threadIdx.x;
  int nwg = gridDim.x;
  int flat = blockIdx.x;
  int sid = (flat & 7) * (nwg >> 3) + (flat >> 3);
  const int lrow0 = sid * 64;

  const int l = tid & 63;
  const int w = tid >> 6;     // 8 waves: 2(M) x 4(N), wave tile 32x64
  const int wm = w >> 2, wn = w & 3;
  const int lr = l & 15, lk = (l >> 4) * 8, q4 = (l >> 4) * 4;

  if (tid < 512) sGate[tid] = gatef[(size_t)(row_base + lrow0) * 8 + tid];

  const ushort* hrow = hg + (size_t)lrow0 * D_H1;

  const ushort* aS; ushort* aD;
  {
    int f = tid * 16;
    int r = f >> 7, ce = (f & 127) >> 1;
    aS = hrow + (size_t)r * D_H1 + ce;
    aD = smA + ((tid * 16) >> 1);
  }
  int bR[4], bC[4]; ushort* bD[4];
  #pragma unroll
  for (int c = 0; c < 4; ++c) {
    int f = c * 8192 + tid * 16;
    bR[c] = f >> 7; bC[c] = (f & 127) >> 1;
    bD[c] = smB + ((c * 8192 + w * 1024) >> 1);
  }
  int oA[2][2], oB[2][4];
  #pragma unroll
  for (int kk = 0; kk < 2; ++kk) {
    #pragma unroll
    for (int mf = 0; mf < 2; ++mf) oA[kk][mf] = kswz(wm * 32 + mf * 16 + lr, kk * 32 + lk);
    #pragma unroll
    for (int nf = 0; nf < 4; ++nf) oB[kk][nf] = kswz(wn * 64 + nf * 16 + lr, kk * 32 + lk);
  }

  f32x4 vacc[2][4] = {};
  __syncthreads();

  for (int e = 0; e < 8; ++e) {
    const ushort* bS[4];
    const ushort* W3 = w3t + (size_t)e * (256 * 256);
    #pragma unroll
    for (int c = 0; c < 4; ++c) bS[c] = W3 + (size_t)bR[c] * 256 + bC[c];
    #pragma unroll
    for (int t4 = 0; t4 < 4; ++t4) {
      gl16(aS, aD); aS += 64;
      #pragma unroll
      for (int c = 0; c < 4; ++c) { gl16(bS[c], bD[c]); bS[c] += 64; }
      __syncthreads();
      #pragma unroll
      for (int kk = 0; kk < 2; ++kk) {
        bf16x8 av[2], bv[4];
        #pragma unroll
        for (int mf = 0; mf < 2; ++mf) av[mf] = *(const bf16x8*)&smA[oA[kk][mf]];
        #pragma unroll
        for (int nf = 0; nf < 4; ++nf) bv[nf] = *(const bf16x8*)&smB[oB[kk][nf]];
        #pragma unroll
        for (int mf = 0; mf < 2; ++mf)
          #pragma unroll
          for (int nf = 0; nf < 4; ++nf)
            vacc[mf][nf] = __builtin_amdgcn_mfma_f32_16x16x32_bf16(av[mf], bv[nf], vacc[mf][nf], 0, 0, 0);
      }
      __syncthreads();
    }
  }

  float* eL = (float*)smB;
  for (int i = tid; i < 2048; i += 512) eL[i] = eb3[i];
  __syncthreads();
  #pragma unroll
  for (int mf = 0; mf < 2; ++mf)
    #pragma unroll
    for (int rg = 0; rg < 4; ++rg) {
      int rr = wm * 32 + mf * 16 + q4 + rg;
      const float* gp = &sGate[rr * 8];
      #pragma unroll
      for (int nf = 0; nf < 4; ++nf) {
        int cc = wn * 64 + nf * 16 + lr;
        float bsum = 0.f;
        #pragma unroll
        for (int ee = 0; ee < 8; ++ee) bsum += gp[ee] * eL[ee * 256 + cc];
        velout[(size_t)(row_base + lrow0 + rr) * D_EMBED + cc] = vacc[mf][nf][rg] + bsum;
      }
    }
}

// ---- FALLBACK (proven): fused moe; gload_lds + kswz; hbuf plain ----
__global__ __launch_bounds__(512) void moe_fused_kernel(
    const ushort* __restrict__ xb, const ushort* __restrict__ w1t,
    const ushort* __restrict__ w2t, const ushort* __restrict__ w3t,
    const float* __restrict__ eb1, const float* __restrict__ eb2,
    const float* __restrict__ eb3, const float* __restrict__ gatef,
    float* __restrict__ velout) {
  __shared__ __align__(16) ushort smA[128 * 64];
  __shared__ __align__(16) ushort smB[256 * 64];
  __shared__ __align__(16) ushort hbuf[128 * HSTR];
  __shared__ float sGate[128 * 8];
  __shared__ float sEb3[8 * 256];

  const int tid = threadIdx.x;
  const int row0 = blockIdx.x * 128;
  const int l = tid & 63;
  const int w = tid >> 6;
  const int wm = w >> 2, wn = w & 3;
  const int lr = l & 15, lk = (l >> 4) * 8, q4 = (l >> 4) * 4;

  for (int i = tid; i < 1024; i += 512) sGate[i] = gatef[(size_t)row0 * 8 + i];
  for (int i = tid; i < 2048; i += 512) sEb3[i] = eb3[i];

  const ushort* xrow = xb + (size_t)row0 * 640;
  f32x4 vacc[4][4] = {};
  __syncthreads();

  for (int e = 0; e < 8; ++e) {
    const ushort* W1 = w1t + (size_t)e * (256 * 640);
    const ushort* W2 = w2t + (size_t)e * (256 * 256);
    const ushort* W3 = w3t + (size_t)e * (256 * 256);

    f32x4 acc[4][4] = {};
    for (int kt = 0; kt < 640; kt += 64) {
      #pragma unroll
      for (int c = 0; c < 2; ++c) {
        int f = c * 8192 + tid * 16;
        int r = f >> 7, ce = (f & 127) >> 1;
        gl16(xrow + (size_t)r * 640 + kt + ce, smA + ((c * 8192 + w * 1024) >> 1));
      }
      #pragma unroll
      for (int c = 0; c < 4; ++c) {
        int f = c * 8192 + tid * 16;
        int r = f >> 7, ce = (f & 127) >> 1;
        gl16(W1 + (size_t)r * 640 + kt + ce, smB + ((c * 8192 + w * 1024) >> 1));
      }
      __syncthreads();
      #pragma unroll
      for (int kk = 0; kk < 2; ++kk) {
        int kb = kk * 32 + lk;
        bf16x8 av[4], bv[4];
        #pragma unroll
        for (int mf = 0; mf < 4; ++mf)
          av[mf] = *(const bf16x8*)&smA[kswz(wm * 64 + mf * 16 + lr, kb)];
        #pragma unroll
        for (int nf = 0; nf < 4; ++nf)
          bv[nf] = *(const bf16x8*)&smB[kswz(wn * 64 + nf * 16 + lr, kb)];
        #pragma unroll
        for (int mf = 0; mf < 4; ++mf)
          #pragma unroll
          for (int nf = 0; nf < 4; ++nf)
            acc[mf][nf] = __builtin_amdgcn_mfma_f32_16x16x32_bf16(av[mf], bv[nf], acc[mf][nf], 0, 0, 0);
      }
      __syncthreads();
    }
    #pragma unroll
    for (int nf = 0; nf < 4; ++nf) {
      int cc = wn * 64 + nf * 16 + lr;
      float b1v = eb1[e * 256 + cc];
      #pragma unroll
      for (int mf = 0; mf < 4; ++mf)
        #pragma unroll
        for (int rg = 0; rg < 4; ++rg) {
          int rr = wm * 64 + mf * 16 + q4 + rg;
          hbuf[rr * HSTR + cc] = f2bf(silu_f(acc[mf][nf][rg] + b1v));
        }
    }
    __syncthreads();

    #pragma unroll
    for (int mf = 0; mf < 4; ++mf)
      #pragma unroll
      for (int nf = 0; nf < 4; ++nf)
        acc[mf][nf] = (f32x4){0.f, 0.f, 0.f, 0.f};
    for (int kt = 0; kt < 256; kt += 64) {
      #pragma unroll
      for (int c = 0; c < 4; ++c) {
        int f = c * 8192 + tid * 16;
        int r = f >> 7, ce = (f & 127) >> 1;
        gl16(W2 + (size_t)r * 256 + kt + ce, smB + ((c * 8192 + w * 1024) >> 1));
      }
      __syncthreads();
      #pragma unroll
      for (int kk = 0; kk < 2; ++kk) {
        int kbl = kk * 32 + lk;
        int kbh = kt + kbl;
        bf16x8 av[4], bv[4];
        #pragma unroll
        for (int mf = 0; mf < 4; ++mf)
          av[mf] = *(const bf16x8*)&hbuf[(wm * 64 + mf * 16 + lr) * HSTR + kbh];
        #pragma unroll
        for (int nf = 0; nf < 4; ++nf)
          bv[nf] = *(const bf16x8*)&smB[kswz(wn * 64 + nf * 16 + lr, kbl)];
        #pragma unroll
        for (int mf = 0; mf < 4; ++mf)
          #pragma unroll
          for (int nf = 0; nf < 4; ++nf)
            acc[mf][nf] = __builtin_amdgcn_mfma_f32_16x16x32_bf16(av[mf], bv[nf], acc[mf][nf], 0, 0, 0);
      }
      __syncthreads();
    }
    #pragma unroll
    for (int nf = 0; nf < 4; ++nf) {
      int cc = wn * 64 + nf * 16 + lr;
      float b2v = eb2[e * 256 + cc];
      #pragma unroll
      for (int mf = 0; mf < 4; ++mf)
        #pragma unroll
        for (int rg = 0; rg < 4; ++rg) {
          int rr = wm * 64 + mf * 16 + q4 + rg;
          float gv = sGate[rr * 8 + e];
          hbuf[rr * HSTR + cc] = f2bf(silu_f(acc[mf][nf][rg] + b2v) * gv);
        }
    }
    __syncthreads();

    for (int kt = 0; kt < 256; kt += 64) {
      #pragma unroll
      for (int c = 0; c < 4; ++c) {
        int f = c * 8192 + tid * 16;
        int r = f >> 7, ce = (f & 127) >> 1;
        gl16(W3 + (size_t)r * 256 + kt + ce, smB + ((c * 8192 + w * 1024) >> 1));
      }
      __syncthreads();
      #pragma unroll
      for (int kk = 0; kk < 2; ++kk) {
        int kbl = kk * 32 + lk;
        int kbh = kt + kbl;
        bf16x8 av[4], bv[4];
        #pragma unroll
        for (int mf = 0; mf < 4; ++mf)
          av[mf] = *(const bf16x8*)&hbuf[(wm * 64 + mf * 16 + lr) * HSTR + kbh];
        #pragma unroll
        for (int nf = 0; nf < 4; ++nf)
          bv[nf] = *(const bf16x8*)&smB[kswz(wn * 64 + nf * 16 + lr, kbl)];
        #pragma unroll
        for (int mf = 0; mf < 4; ++mf)
          #pragma unroll
          for (int nf = 0; nf < 4; ++nf)
            vacc[mf][nf] = __builtin_amdgcn_mfma_f32_16x16x32_bf16(av[mf], bv[nf], vacc[mf][nf], 0, 0, 0);
      }
      __syncthreads();
    }
  }

  #pragma unroll
  for (int mf = 0; mf < 4; ++mf)
    #pragma unroll
    for (int rg = 0; rg < 4; ++rg) {
      int rr = wm * 64 + mf * 16 + q4 + rg;
      const float* gp = &sGate[rr * 8];
      #pragma unroll
      for (int nf = 0; nf < 4; ++nf) {
        int cc = wn * 64 + nf * 16 + lr;
        float bsum = 0.f;
        #pragma unroll
        for (int ee = 0; ee < 8; ++ee) bsum += gp[ee] * sEb3[ee * 256 + cc];
        velout[(size_t)(row0 + rr) * D_EMBED + cc] = vacc[mf][nf][rg] + bsum;
      }
    }
}

extern "C" void kernel_launch(void* const* d_in, const int* in_sizes, int n_in,
                              void* d_out, int out_size, void* d_ws, size_t ws_size,
                              hipStream_t stream) {
  const float* zt   = (const float*)d_in[0];
  const float* tin  = (const float*)d_in[1];
  const float* cond = (const float*)d_in[2];
  const float* tW1  = (const float*)d_in[3];
  const float* tb1  = (const float*)d_in[4];
  const float* tW2  = (const float*)d_in[5];
  const float* tb2  = (const float*)d_in[6];
  const float* eW1  = (const float*)d_in[7];
  const float* eb1  = (const float*)d_in[8];
  const float* eW2  = (const float*)d_in[9];
  const float* eb2  = (const float*)d_in[10];
  const float* eW3  = (const float*)d_in[11];
  const float* eb3  = (const float*)d_in[12];
  const float* rW1  = (const float*)d_in[13];
  const float* rb1  = (const float*)d_in[14];
  const float* rW2  = (const float*)d_in[15];
  const float* rb2  = (const float*)d_in[16];

  char* wp = (char*)d_ws;
  ushort* xb    = (ushort*)wp; wp += (size_t)NB_ROWS * D_IN * 2;
  float*  gatef = (float*)wp;  wp += (size_t)NB_ROWS * 8 * 4;
  ushort* w1t   = (ushort*)wp; wp += (size_t)N_EXP * D_HID * D_IN * 2;
  ushort* w2t   = (ushort*)wp; wp += (size_t)N_EXP * D_HID * D_HID * 2;
  ushort* w3t   = (ushort*)wp; wp += (size_t)N_EXP * D_HID * D_EMBED * 2;
  ushort* rw1t  = (ushort*)wp; wp += (size_t)D_RHID * D_IN * 2;
  ushort* tw1t  = (ushort*)wp; wp += (size_t)128 * 128 * 2;
  ushort* tw2t  = (ushort*)wp; wp += (size_t)128 * 128 * 2;
  ushort* hg    = (ushort*)wp;
  size_t base = (size_t)(wp - (char*)d_ws);

  int CH = 0;
  for (int cand = NB_ROWS; cand >= 8192; cand >>= 1) {
    if (base + (size_t)cand * D_H1 * 2 <= ws_size) { CH = cand; break; }
  }

  float* velout  = (float*)d_out;
  float* gateout = velout + (size_t)NB_ROWS * D_EMBED;

  prep_all<<<(2473984 + 255) / 256, 256, 0, stream>>>(
      tW1, tW2, rW1, eW1, eW2, eW3, tw1t, tw2t, rw1t, w1t, w2t, w3t);

  time_x_kernel<<<512, 512, 0, stream>>>(zt, tin, cond, tw1t, tw2t, tb1, tb2, xb);
  router_kernel<<<512, 256, 0, stream>>>(xb, rw1t, rb1, rW2, rb2, gatef, gateout);

  if (CH > 0) {
    for (int r0 = 0; r0 < NB_ROWS; r0 += CH) {
      moe_h1_kernel<<<(CH / 128) * 8, 512, 0, stream>>>(xb, w1t, eb1, hg, r0);
      moe_h2_kernel<<<(CH / 128) * 8, 512, 0, stream>>>(hg, w2t, eb2, gatef, r0);
      moe_vel_kernel<<<CH / 64, 512, 0, stream>>>(hg, w3t, eb3, gatef, velout, r0);
    }
  } else {
    moe_fused_kernel<<<512, 512, 0, stream>>>(xb, w1t, w2t, w3t,
                                              eb1, eb2, eb3, gatef, velout);
  }
}